// Round 10
// baseline (1486.318 us; speedup 1.0000x reference)
//
#include <hip/hip_runtime.h>
#include <math.h>

typedef unsigned int uint;
typedef unsigned short ushort;

// Dims
constexpr int BB  = 128;
constexpr int TT  = 512;
constexpr int DIN = 88;
constexpr int DZ  = 80;
constexpr int DH  = 400;
constexpr int DE  = 100;
constexpr int DTR = 200;
constexpr int DOUT = DIN + DZ + DZ; // 248

typedef __attribute__((ext_vector_type(8))) short bf16x8;
typedef __attribute__((ext_vector_type(4))) float f32x4;
typedef __attribute__((ext_vector_type(4))) uint  u32x4;
union FU { u32x4 u; bf16x8 v; };

__device__ __forceinline__ float softplusf(float x) {
    return fmaxf(x, 0.f) + log1pf(__expf(-fabsf(x)));
}
__device__ __forceinline__ float sigmoidf(float x) {
    return 1.f / (1.f + __expf(-x));
}
__device__ __forceinline__ uint bf16rn(float f) {
    uint u = __float_as_uint(f);
    return (u + 0x7FFFu + ((u >> 16) & 1u)) >> 16;
}
__device__ __forceinline__ uint pk2(float lo, float hi) {
    return bf16rn(lo) | (bf16rn(hi) << 16);
}
__device__ __forceinline__ bf16x8 fragF32(const float* p) {
    float4 f0 = *(const float4*)p, f1 = *(const float4*)(p + 4);
    FU fu;
    fu.u.x = pk2(f0.x, f0.y); fu.u.y = pk2(f0.z, f0.w);
    fu.u.z = pk2(f1.x, f1.y); fu.u.w = pk2(f1.z, f1.w);
    return fu.v;
}
__device__ __forceinline__ bf16x8 fragF32relu(const float* p) {
    float4 f0 = *(const float4*)p, f1 = *(const float4*)(p + 4);
    FU fu;
    fu.u.x = pk2(fmaxf(f0.x, 0.f), fmaxf(f0.y, 0.f));
    fu.u.y = pk2(fmaxf(f0.z, 0.f), fmaxf(f0.w, 0.f));
    fu.u.z = pk2(fmaxf(f1.x, 0.f), fmaxf(f1.y, 0.f));
    fu.u.w = pk2(fmaxf(f1.z, 0.f), fmaxf(f1.w, 0.f));
    return fu.v;
}
#define MFMA(A, B, C) __builtin_amdgcn_mfma_f32_16x16x32_bf16((A), (B), (C), 0, 0, 0)

// ---------------- fused weight pack ----------------
struct Srcs { const float* p[13]; };

__global__ __launch_bounds__(256) void packall_kernel(Srcs s, uint* __restrict__ dst) {
    constexpr int O_[13]   = {80,80,200,200,80,80,80,80,100,100,88,400,400};
    constexpr int K_[13]   = {400,400,80,80,200,200,80,80,80,100,100,88,400};
    constexpr int KS_[13]  = {13,13,3,3,7,7,3,3,3,4,4,3,13};
    constexpr int OFF_[13] = {0,65,130,169,208,243,278,293,308,332,364,388,463};
    int tile = blockIdx.x;
    int e = 0;
    #pragma unroll
    for (int i = 1; i < 13; ++i) if (tile >= OFF_[i]) e = i;
    int lt = tile - OFF_[e];
    int nt = lt / KS_[e], ks = lt % KS_[e];
    const float* W = s.p[e];
    int r = threadIdx.x, l = r >> 2, d = r & 3;
    int o = nt * 16 + (l & 15);
    int k = ks * 32 + ((l >> 4) << 3) + 2 * d;
    uint lo = 0, hi = 0;
    if (o < O_[e] && k < K_[e])     lo = bf16rn(W[o * K_[e] + k]);
    if (o < O_[e] && k + 1 < K_[e]) hi = bf16rn(W[o * K_[e] + k + 1]);
    dst[(size_t)tile * 256 + r] = lo | (hi << 16);
}

constexpr int WHH = 463;   // W_hh tiles: WHH + mt*13 + ks; 25 M-tiles

// ---------------- pre GEMM (MFMA), fp32 output ----------------
__global__ __launch_bounds__(256) void pre_kernel(
    const float* __restrict__ x, const uint* __restrict__ bt,
    const float* __restrict__ b_ih, const float* __restrict__ b_hh,
    float* __restrict__ pre) {
    __shared__ float xs[16 * 100];
    const int b = blockIdx.y, tt0 = blockIdx.x * 16, tid = threadIdx.x;
    const int l = tid & 63, wid = tid >> 6, lr = l & 15, lg = l >> 4;
    for (int idx = tid; idx < 1600; idx += 256) {
        int r = idx / 100, k = idx % 100;
        xs[idx] = (k < DIN) ? x[((size_t)b * TT + (TT - 1 - (tt0 + r))) * DIN + k] : 0.f;
    }
    __syncthreads();
    bf16x8 af[3];
    #pragma unroll
    for (int ks = 0; ks < 3; ++ks) af[ks] = fragF32(xs + lr * 100 + ks * 32 + lg * 8);
    const uint4* bt4 = (const uint4*)bt;
    for (int nt = wid; nt < 25; nt += 4) {
        f32x4 acc = {0.f, 0.f, 0.f, 0.f};
        const uint4* bp = bt4 + (size_t)(388 + nt * 3) * 64 + l;
        #pragma unroll
        for (int ks = 0; ks < 3; ++ks) { FU bu; bu.u = *(const u32x4*)(bp + ks * 64); acc = MFMA(af[ks], bu.v, acc); }
        int col = nt * 16 + lr;
        float bias = b_ih[col] + b_hh[col];
        #pragma unroll
        for (int i = 0; i < 4; ++i)
            pre[((size_t)b * TT + tt0 + lg * 4 + i) * DH + col] = acc[i] + bias;
    }
}

// ---------------- serial RNN scan (MFMA, 16 batches/block, 8 blocks, 4 waves) ----------------
// Round-7 structure with 4 waves x 6 register tiles (mt = wid + 4s) + wave-0
// tile 24 from LDS. pb LDS staging of fp32 pre (depth-1); in-place bf16 hs write
// into first 200 dwords of consumed pre row; plain __syncthreads per step.
__device__ __forceinline__ void rnn_emit(int mt, f32x4 c, const float* pcur,
                                         uint* hn, uint* grow, int batch, int lg) {
    float4 pr = *(const float4*)(pcur + batch * 404 + mt * 16 + lg * 4);
    uint d0 = pk2(fmaxf(c[0] + pr.x, 0.f), fmaxf(c[1] + pr.y, 0.f));
    uint d1 = pk2(fmaxf(c[2] + pr.z, 0.f), fmaxf(c[3] + pr.w, 0.f));
    uint2 dd = make_uint2(d0, d1);
    *(uint2*)(hn + batch * 212 + mt * 8 + lg * 2) = dd;
    *(uint2*)(grow + mt * 8 + lg * 2) = dd;
}

__global__ __launch_bounds__(256) __attribute__((amdgpu_waves_per_eu(1, 1)))
void rnn_kernel(const u32x4* __restrict__ bt4, const float* __restrict__ h0,
                float* __restrict__ prehs) {
    extern __shared__ char smem[];
    uint*  hb   = (uint*)smem;                       // [2][16][212] packed bf16 h
    float* pb   = (float*)(smem + 27136);            // [2][16][404] staged pre (fp32)
    u32x4* wt24 = (u32x4*)(smem + 27136 + 51712);    // [13*64] tile-24 W frags

    const int tid = threadIdx.x, lane = tid & 63, wid = tid >> 6;   // wid 0..3
    const int batch = lane & 15, lg = lane >> 4;
    const int b0 = blockIdx.x * 16;

    // Register-resident A tiles: wave w -> mt = w + 4s, s = 0..5
    u32x4 A[6][13];
    #pragma unroll
    for (int s = 0; s < 6; ++s) {
        const u32x4* base = bt4 + (size_t)(WHH + (wid + 4 * s) * 13) * 64 + lane;
        #pragma unroll
        for (int ks = 0; ks < 13; ++ks) A[s][ks] = base[ks * 64];
    }
    #pragma unroll
    for (int s = 0; s < 6; ++s) {
        #pragma unroll
        for (int ks = 0; ks < 13; ++ks) asm volatile("" : "+v"(A[s][ks]));
    }

    for (int i = tid; i < 13 * 64; i += 256)
        wt24[i] = bt4[(size_t)(WHH + 24 * 13) * 64 + i];
    for (int i = tid; i < 2 * 16 * 12; i += 256) {           // zero hb pads
        int buf = i / 192, r = i % 192;
        hb[buf * 3392 + (r / 12) * 212 + 200 + r % 12] = 0u;
    }
    for (int i = tid; i < 16 * 200; i += 256) {              // h0 -> buf0
        int bs = i / 200, d = i % 200;
        hb[bs * 212 + d] = pk2(h0[2 * d], h0[2 * d + 1]);
    }
    // stage pre_0: wave w -> batches 4w..4w+3
    #pragma unroll
    for (int r = 0; r < 4; ++r) {
        const u32x4* ra = (const u32x4*)(prehs + ((size_t)(b0 + 4 * wid + r) * TT) * DH);
        u32x4* wa = (u32x4*)(pb + (4 * wid + r) * 404);
        wa[lane] = ra[lane];
        if (lane < 36) wa[64 + lane] = ra[64 + lane];
    }
    __syncthreads();

    uint cur = 0;
    for (int tt = 0; tt < TT; ++tt) {
        // issue next-step pre loads early (hide under MFMA)
        u32x4 z4 = {0u, 0u, 0u, 0u};
        u32x4 n0a = z4, n0b = z4, n1a = z4, n1b = z4;
        u32x4 n2a = z4, n2b = z4, n3a = z4, n3b = z4;
        const bool hasNext = (tt + 1 < TT);
        if (hasNext) {
            const u32x4* r0 = (const u32x4*)(prehs + ((size_t)(b0 + 4 * wid + 0) * TT + tt + 1) * DH);
            const u32x4* r1 = (const u32x4*)(prehs + ((size_t)(b0 + 4 * wid + 1) * TT + tt + 1) * DH);
            const u32x4* r2 = (const u32x4*)(prehs + ((size_t)(b0 + 4 * wid + 2) * TT + tt + 1) * DH);
            const u32x4* r3 = (const u32x4*)(prehs + ((size_t)(b0 + 4 * wid + 3) * TT + tt + 1) * DH);
            n0a = r0[lane]; n1a = r1[lane]; n2a = r2[lane]; n3a = r3[lane];
            if (lane < 36) {
                n0b = r0[64 + lane]; n1b = r1[64 + lane];
                n2b = r2[64 + lane]; n3b = r3[64 + lane];
            }
        }

        const uint*  hcur = hb + cur * 3392;
        const float* pcur = pb + cur * (16 * 404);
        f32x4 c0 = {0.f, 0.f, 0.f, 0.f}, c1 = c0, c2 = c0, c3 = c0, c4 = c0, c5 = c0, c24 = c0;
        const u32x4* hrow = (const u32x4*)(hcur + batch * 212);
        #pragma unroll
        for (int ks = 0; ks < 13; ++ks) {
            FU b; b.u = hrow[ks * 4 + lg];
            FU a0; a0.u = A[0][ks]; c0 = MFMA(a0.v, b.v, c0);
            FU a1; a1.u = A[1][ks]; c1 = MFMA(a1.v, b.v, c1);
            FU a2; a2.u = A[2][ks]; c2 = MFMA(a2.v, b.v, c2);
            FU a3; a3.u = A[3][ks]; c3 = MFMA(a3.v, b.v, c3);
            FU a4; a4.u = A[4][ks]; c4 = MFMA(a4.v, b.v, c4);
            FU a5; a5.u = A[5][ks]; c5 = MFMA(a5.v, b.v, c5);
            if (wid == 0) { FU w; w.u = wt24[ks * 64 + lane]; c24 = MFMA(w.v, b.v, c24); }
        }

        uint*  hnxt = hb + (cur ^ 1) * 3392;
        float* pnxt = pb + (cur ^ 1) * (16 * 404);
        uint*  grow = (uint*)prehs + ((size_t)(b0 + batch) * TT + tt) * DH;

        rnn_emit(wid + 0,  c0, pcur, hnxt, grow, batch, lg);
        rnn_emit(wid + 4,  c1, pcur, hnxt, grow, batch, lg);
        rnn_emit(wid + 8,  c2, pcur, hnxt, grow, batch, lg);
        rnn_emit(wid + 12, c3, pcur, hnxt, grow, batch, lg);
        rnn_emit(wid + 16, c4, pcur, hnxt, grow, batch, lg);
        rnn_emit(wid + 20, c5, pcur, hnxt, grow, batch, lg);
        if (wid == 0) rnn_emit(24, c24, pcur, hnxt, grow, batch, lg);

        if (hasNext) {
            u32x4* w0 = (u32x4*)(pnxt + (4 * wid + 0) * 404);
            u32x4* w1 = (u32x4*)(pnxt + (4 * wid + 1) * 404);
            u32x4* w2 = (u32x4*)(pnxt + (4 * wid + 2) * 404);
            u32x4* w3 = (u32x4*)(pnxt + (4 * wid + 3) * 404);
            w0[lane] = n0a; w1[lane] = n1a; w2[lane] = n2a; w3[lane] = n3a;
            if (lane < 36) {
                w0[64 + lane] = n0b; w1[64 + lane] = n1b;
                w2[64 + lane] = n2b; w3[64 + lane] = n3b;
            }
        }
        __syncthreads();
        cur ^= 1;
    }
}

// ---------------- fused downstream (MFMA; hs = first 50 uint4 of 100-uint4 rows) ----------------
__global__ __launch_bounds__(256) void e_kernel(
    const uint4* __restrict__ hs4, const float* __restrict__ eps,
    const float* __restrict__ z0, const uint* __restrict__ bt,
    const float* __restrict__ b_loc, const float* __restrict__ b_scale,
    const float* __restrict__ gb1, const float* __restrict__ pb1,
    const float* __restrict__ gb2, const float* __restrict__ pb2,
    const float* __restrict__ lb,  const float* __restrict__ sb,
    const float* __restrict__ eb1, const float* __restrict__ eb2,
    const float* __restrict__ eb3, float* __restrict__ out) {
    __shared__ float lds[12196];
    float* zl = lds;              // [17][100] fp32, cols 80-99 zero
    float* AP = lds + 1700;       // A:[16][228] | P at +3648; zpre overlays (stride 164)
    float* gp = lds + 8996;       // gate [16][100] | prop at +1600

    const int tid = threadIdx.x, l = tid & 63, wid = tid >> 6;
    const int b = blockIdx.y, t0 = blockIdx.x * 16;
    const int lr = l & 15, lg = l >> 4;
    const uint4* bt4 = (const uint4*)bt;

    bf16x8 zf[3];

    // ---- P1: zpre = hs_rows @ [W_loc|W_scale]^T ----
    {
        const int m0 = (wid >> 1) * 16;
        int r = m0 + lr;
        int t = t0 - 1 + r; t = min(max(t, 0), TT - 1);
        const uint4* rp = hs4 + ((size_t)b * TT + (TT - 1 - t)) * 100;
        bf16x8 af[13];
        FU zz; zz.u = (u32x4){0u, 0u, 0u, 0u};
        #pragma unroll
        for (int ks = 0; ks < 13; ++ks) {
            if (ks == 12 && lg >= 2) af[ks] = zz.v;
            else { FU fu; fu.u = *(const u32x4*)(rp + ks * 4 + lg); af[ks] = fu.v; }
        }
        for (int nt = (wid & 1); nt < 10; nt += 2) {
            f32x4 acc = {0.f, 0.f, 0.f, 0.f};
            const uint4* bp = bt4 + (size_t)(nt * 13) * 64 + l;
            #pragma unroll
            for (int ks = 0; ks < 13; ++ks) { FU bu; bu.u = *(const u32x4*)(bp + ks * 64); acc = MFMA(af[ks], bu.v, acc); }
            int col = nt * 16 + lr;
            float bias = (col < DZ) ? b_loc[col] : b_scale[col - DZ];
            #pragma unroll
            for (int i = 0; i < 4; ++i) {
                int rr = m0 + lg * 4 + i;
                if (rr < 17) AP[rr * 164 + col] = acc[i] + bias;
            }
        }
    }
    __syncthreads();

    // ---- P1b: z = zloc + softplus(zscale)*eps ----
    for (int idx = tid; idx < 17 * 100; idx += 256) {
        int r = idx / 100, o = idx % 100;
        float zv = 0.f;
        if (o < DZ) {
            int t = t0 - 1 + r;
            if (t < 0) zv = z0[o];
            else {
                float sp = softplusf(AP[r * 164 + DZ + o]);
                zv = AP[r * 164 + o] + sp * eps[((size_t)b * TT + t) * DZ + o];
            }
        }
        zl[idx] = zv;
    }
    __syncthreads();

    // ---- P2: A/P = relu(z_shift @ {gW1,pW1}^T) ----
    {
        #pragma unroll
        for (int ks = 0; ks < 3; ++ks) zf[ks] = fragF32(zl + lr * 100 + ks * 32 + lg * 8);
        for (int idx = tid; idx < 640; idx += 256) {
            int h = idx / 320, rem = idx % 320;
            AP[h * 3648 + (rem / 20) * 228 + 208 + rem % 20] = 0.f;
        }
        for (int nt = wid; nt < 26; nt += 4) {
            f32x4 acc = {0.f, 0.f, 0.f, 0.f};
            const uint4* bp = bt4 + (size_t)(130 + nt * 3) * 64 + l;
            #pragma unroll
            for (int ks = 0; ks < 3; ++ks) { FU bu; bu.u = *(const u32x4*)(bp + ks * 64); acc = MFMA(zf[ks], bu.v, acc); }
            int isP = nt >= 13;
            int col = (isP ? nt - 13 : nt) * 16 + lr;
            float bias = (col < DTR) ? (isP ? pb1[col] : gb1[col]) : 0.f;
            float* dst = AP + isP * 3648;
            #pragma unroll
            for (int i = 0; i < 4; ++i)
                dst[(lg * 4 + i) * 228 + col] = fmaxf(acc[i] + bias, 0.f);
        }
    }
    __syncthreads();

    // ---- P3: gate = sigmoid(A@gW2^T), prop = P@pW2^T ----
    {
        int half = wid >> 1;
        const float* src = AP + half * 3648;
        bf16x8 apf[7];
        #pragma unroll
        for (int ks = 0; ks < 7; ++ks) apf[ks] = fragF32(src + lr * 228 + ks * 32 + lg * 8);
        for (int idx = tid; idx < 640; idx += 256) {
            int h = idx / 320, rem = idx % 320;
            gp[h * 1600 + (rem / 20) * 100 + 80 + rem % 20] = 0.f;
        }
        for (int nt = (wid & 1); nt < 5; nt += 2) {
            f32x4 acc = {0.f, 0.f, 0.f, 0.f};
            const uint4* bp = bt4 + (size_t)(208 + half * 35 + nt * 7) * 64 + l;
            #pragma unroll
            for (int ks = 0; ks < 7; ++ks) { FU bu; bu.u = *(const u32x4*)(bp + ks * 64); acc = MFMA(apf[ks], bu.v, acc); }
            int col = nt * 16 + lr;
            float bias = half ? pb2[col] : gb2[col];
            float* dst = gp + half * 1600;
            #pragma unroll
            for (int i = 0; i < 4; ++i) {
                float v = acc[i] + bias;
                dst[(lg * 4 + i) * 100 + col] = half ? v : sigmoidf(v);
            }
        }
    }
    __syncthreads();

    // ---- P4 (trans_loc/trans_scale) + P5 (h1) ----
    {
        bf16x8 z1f[3], prf[3];
        #pragma unroll
        for (int ks = 0; ks < 3; ++ks) {
            z1f[ks] = fragF32(zl + (1 + lr) * 100 + ks * 32 + lg * 8);
            prf[ks] = fragF32relu(gp + 1600 + lr * 100 + ks * 32 + lg * 8);
        }
        for (int tsk = wid; tsk < 18; tsk += 4) {
            if (tsk < 5) {
                f32x4 acc = {0.f, 0.f, 0.f, 0.f};
                const uint4* bp = bt4 + (size_t)(278 + tsk * 3) * 64 + l;
                #pragma unroll
                for (int ks = 0; ks < 3; ++ks) { FU bu; bu.u = *(const u32x4*)(bp + ks * 64); acc = MFMA(zf[ks], bu.v, acc); }
                int col = tsk * 16 + lr;
                float bias = lb[col];
                #pragma unroll
                for (int i = 0; i < 4; ++i) {
                    int rr = lg * 4 + i;
                    float g  = gp[rr * 100 + col];
                    float pv = gp[1600 + rr * 100 + col];
                    out[((size_t)b * TT + t0 + rr) * DOUT + DIN + col] =
                        (1.f - g) * (acc[i] + bias) + g * pv;
                }
            } else if (tsk < 10) {
                int nt = tsk - 5;
                f32x4 acc = {0.f, 0.f, 0.f, 0.f};
                const uint4* bp = bt4 + (size_t)(293 + nt * 3) * 64 + l;
                #pragma unroll
                for (int ks = 0; ks < 3; ++ks) { FU bu; bu.u = *(const u32x4*)(bp + ks * 64); acc = MFMA(prf[ks], bu.v, acc); }
                int col = nt * 16 + lr;
                float bias = sb[col];
                #pragma unroll
                for (int i = 0; i < 4; ++i)
                    out[((size_t)b * TT + t0 + lg * 4 + i) * DOUT + DIN + DZ + col] =
                        softplusf(acc[i] + bias);
            } else {
                int nt = tsk - 10;
                f32x4 acc = {0.f, 0.f, 0.f, 0.f};
                const uint4* bp = bt4 + (size_t)(308 + nt * 3) * 64 + l;
                #pragma unroll
                for (int ks = 0; ks < 3; ++ks) { FU bu; bu.u = *(const u32x4*)(bp + ks * 64); acc = MFMA(z1f[ks], bu.v, acc); }
                int col = nt * 16 + lr;
                float bias = (col < DE) ? eb1[col] : 0.f;
                #pragma unroll
                for (int i = 0; i < 4; ++i)
                    AP[(lg * 4 + i) * 228 + col] = fmaxf(acc[i] + bias, 0.f);
            }
        }
    }
    __syncthreads();

    // ---- P6: h2 = relu(h1 @ eW2^T) ----
    {
        bf16x8 hf[4];
        #pragma unroll
        for (int ks = 0; ks < 4; ++ks) hf[ks] = fragF32(AP + lr * 228 + ks * 32 + lg * 8);
        for (int nt = wid; nt < 8; nt += 4) {
            f32x4 acc = {0.f, 0.f, 0.f, 0.f};
            const uint4* bp = bt4 + (size_t)(332 + nt * 4) * 64 + l;
            #pragma unroll
            for (int ks = 0; ks < 4; ++ks) { FU bu; bu.u = *(const u32x4*)(bp + ks * 64); acc = MFMA(hf[ks], bu.v, acc); }
            int col = nt * 16 + lr;
            float bias = (col < DE) ? eb2[col] : 0.f;
            #pragma unroll
            for (int i = 0; i < 4; ++i)
                AP[3648 + (lg * 4 + i) * 228 + col] = fmaxf(acc[i] + bias, 0.f);
        }
    }
    __syncthreads();

    // ---- P7: emis = sigmoid(h2 @ eW3^T) ----
    {
        bf16x8 hf[4];
        #pragma unroll
        for (int ks = 0; ks < 4; ++ks) hf[ks] = fragF32(AP + 3648 + lr * 228 + ks * 32 + lg * 8);
        for (int nt = wid; nt < 6; nt += 4) {
            f32x4 acc = {0.f, 0.f, 0.f, 0.f};
            const uint4* bp = bt4 + (size_t)(364 + nt * 4) * 64 + l;
            #pragma unroll
            for (int ks = 0; ks < 4; ++ks) { FU bu; bu.u = *(const u32x4*)(bp + ks * 64); acc = MFMA(hf[ks], bu.v, acc); }
            int col = nt * 16 + lr;
            if (col < DIN) {
                float bias = eb3[col];
                #pragma unroll
                for (int i = 0; i < 4; ++i)
                    out[((size_t)b * TT + t0 + lg * 4 + i) * DOUT + col] = sigmoidf(acc[i] + bias);
            }
        }
    }
}

extern "C" void kernel_launch(void* const* d_in, const int* in_sizes, int n_in,
                              void* d_out, int out_size, void* d_ws, size_t ws_size,
                              hipStream_t stream) {
    const float* x       = (const float*)d_in[0];
    const float* eps     = (const float*)d_in[1];
    const float* W_ih    = (const float*)d_in[2];
    const float* W_hh    = (const float*)d_in[3];
    const float* b_ih    = (const float*)d_in[4];
    const float* b_hh    = (const float*)d_in[5];
    const float* h0      = (const float*)d_in[6];
    const float* z0      = (const float*)d_in[7];
    const float* W_loc   = (const float*)d_in[8];
    const float* b_loc   = (const float*)d_in[9];
    const float* W_scale = (const float*)d_in[10];
    const float* b_scale = (const float*)d_in[11];
    const float* gW1 = (const float*)d_in[12];
    const float* gb1 = (const float*)d_in[13];
    const float* gW2 = (const float*)d_in[14];
    const float* gb2 = (const float*)d_in[15];
    const float* pW1 = (const float*)d_in[16];
    const float* pb1 = (const float*)d_in[17];
    const float* pW2 = (const float*)d_in[18];
    const float* pb2 = (const float*)d_in[19];
    const float* sW  = (const float*)d_in[20];
    const float* sb  = (const float*)d_in[21];
    const float* lW  = (const float*)d_in[22];
    const float* lb  = (const float*)d_in[23];
    const float* eW1 = (const float*)d_in[24];
    const float* eb1 = (const float*)d_in[25];
    const float* eW2 = (const float*)d_in[26];
    const float* eb2 = (const float*)d_in[27];
    const float* eW3 = (const float*)d_in[28];
    const float* eb3 = (const float*)d_in[29];

    float* wsf = (float*)d_ws;
    float* prebuf = wsf;                               // B*T*DH floats (pre -> hs bf16 in-place)
    uint*  bt = (uint*)(wsf + (size_t)BB * TT * DH);   // 788 tiles * 256 dwords

    Srcs s;
    s.p[0] = W_loc;  s.p[1] = W_scale; s.p[2] = gW1; s.p[3] = pW1;
    s.p[4] = gW2;    s.p[5] = pW2;     s.p[6] = lW;  s.p[7] = sW;
    s.p[8] = eW1;    s.p[9] = eW2;     s.p[10] = eW3; s.p[11] = W_ih; s.p[12] = W_hh;
    packall_kernel<<<788, 256, 0, stream>>>(s, bt);

    pre_kernel<<<dim3(TT / 16, BB), 256, 0, stream>>>(x, bt, b_ih, b_hh, prebuf);

    size_t smem = 27136 + 51712 + 13312;   // 92160 B
    hipFuncSetAttribute((const void*)rnn_kernel,
                        hipFuncAttributeMaxDynamicSharedMemorySize, (int)smem);
    rnn_kernel<<<dim3(8), dim3(256), smem, stream>>>((const u32x4*)bt, h0, prebuf);

    e_kernel<<<dim3(TT / 16, BB), 256, 0, stream>>>(
        (const uint4*)prebuf, eps, z0, bt,
        b_loc, b_scale, gb1, pb1, gb2, pb2, lb, sb, eb1, eb2, eb3,
        (float*)d_out);
}

// Round 11
// 1150.177 us; speedup vs baseline: 1.2923x; 1.2923x over previous
//
#include <hip/hip_runtime.h>
#include <math.h>

typedef unsigned int uint;
typedef unsigned short ushort;

// Dims
constexpr int BB  = 128;
constexpr int TT  = 512;
constexpr int DIN = 88;
constexpr int DZ  = 80;
constexpr int DH  = 400;
constexpr int DE  = 100;
constexpr int DTR = 200;
constexpr int DOUT = DIN + DZ + DZ; // 248

typedef __attribute__((ext_vector_type(8))) short bf16x8;
typedef __attribute__((ext_vector_type(4))) float f32x4;
typedef __attribute__((ext_vector_type(4))) uint  u32x4;
union FU { u32x4 u; bf16x8 v; };

__device__ __forceinline__ float softplusf(float x) {
    return fmaxf(x, 0.f) + log1pf(__expf(-fabsf(x)));
}
__device__ __forceinline__ float sigmoidf(float x) {
    return 1.f / (1.f + __expf(-x));
}
__device__ __forceinline__ uint bf16rn(float f) {
    uint u = __float_as_uint(f);
    return (u + 0x7FFFu + ((u >> 16) & 1u)) >> 16;
}
__device__ __forceinline__ uint pk2(float lo, float hi) {
    return bf16rn(lo) | (bf16rn(hi) << 16);
}
__device__ __forceinline__ bf16x8 fragF32(const float* p) {
    float4 f0 = *(const float4*)p, f1 = *(const float4*)(p + 4);
    FU fu;
    fu.u.x = pk2(f0.x, f0.y); fu.u.y = pk2(f0.z, f0.w);
    fu.u.z = pk2(f1.x, f1.y); fu.u.w = pk2(f1.z, f1.w);
    return fu.v;
}
__device__ __forceinline__ bf16x8 fragF32relu(const float* p) {
    float4 f0 = *(const float4*)p, f1 = *(const float4*)(p + 4);
    FU fu;
    fu.u.x = pk2(fmaxf(f0.x, 0.f), fmaxf(f0.y, 0.f));
    fu.u.y = pk2(fmaxf(f0.z, 0.f), fmaxf(f0.w, 0.f));
    fu.u.z = pk2(fmaxf(f1.x, 0.f), fmaxf(f1.y, 0.f));
    fu.u.w = pk2(fmaxf(f1.z, 0.f), fmaxf(f1.w, 0.f));
    return fu.v;
}
#define MFMA(A, B, C) __builtin_amdgcn_mfma_f32_16x16x32_bf16((A), (B), (C), 0, 0, 0)
// v_dot2_f32_bf16: ACC += W.lo*H.lo + W.hi*H.hi (bf16 pairs, fp32 accumulate)
#define DOT2(ACC, Wv, Hv) asm("v_dot2_f32_bf16 %0, %1, %2, %0" : "+v"(ACC) : "v"(Wv), "v"(Hv))

// ---------------- fused weight pack (MFMA tiles, unchanged) ----------------
struct Srcs { const float* p[13]; };

__global__ __launch_bounds__(256) void packall_kernel(Srcs s, uint* __restrict__ dst) {
    constexpr int O_[13]   = {80,80,200,200,80,80,80,80,100,100,88,400,400};
    constexpr int K_[13]   = {400,400,80,80,200,200,80,80,80,100,100,88,400};
    constexpr int KS_[13]  = {13,13,3,3,7,7,3,3,3,4,4,3,13};
    constexpr int OFF_[13] = {0,65,130,169,208,243,278,293,308,332,364,388,463};
    int tile = blockIdx.x;
    int e = 0;
    #pragma unroll
    for (int i = 1; i < 13; ++i) if (tile >= OFF_[i]) e = i;
    int lt = tile - OFF_[e];
    int nt = lt / KS_[e], ks = lt % KS_[e];
    const float* W = s.p[e];
    int r = threadIdx.x, l = r >> 2, d = r & 3;
    int o = nt * 16 + (l & 15);
    int k = ks * 32 + ((l >> 4) << 3) + 2 * d;
    uint lo = 0, hi = 0;
    if (o < O_[e] && k < K_[e])     lo = bf16rn(W[o * K_[e] + k]);
    if (o < O_[e] && k + 1 < K_[e]) hi = bf16rn(W[o * K_[e] + k + 1]);
    dst[(size_t)tile * 256 + r] = lo | (hi << 16);
}

// Pack W_hh into per-thread bf16-pair dwords for the dot2 rnn (round-5 layout).
// t<200: p=t, k-half 0 (kd 0..99); 256<=t<456: p=t-256, k-half 1 (kd 100..199).
// dword j (0..199): row = 2p + (j>=100), kd = half*100 + j%100.
// Stored uint4-interleaved: Wb[(j>>2)*2048 + t*4 + (j&3)].
__global__ void pack_rnn(const float* __restrict__ W_hh, uint* __restrict__ Wb) {
    int idx = blockIdx.x * 256 + threadIdx.x;
    if (idx >= 200 * 512) return;
    int t = idx & 511, j = idx >> 9;
    uint val = 0u;
    int p = -1, hf = 0;
    if (t < 200) { p = t; hf = 0; }
    else if (t >= 256 && t < 456) { p = t - 256; hf = 1; }
    if (p >= 0) {
        int r  = 2 * p + (j >= 100 ? 1 : 0);
        int kd = hf * 100 + (j % 100);
        val = pk2(W_hh[r * DH + 2 * kd], W_hh[r * DH + 2 * kd + 1]);
    }
    Wb[(j >> 2) * 2048 + t * 4 + (j & 3)] = val;
}

// ---------------- pre GEMM (MFMA), fp32 output (round-10 proven) ----------------
__global__ __launch_bounds__(256) void pre_kernel(
    const float* __restrict__ x, const uint* __restrict__ bt,
    const float* __restrict__ b_ih, const float* __restrict__ b_hh,
    float* __restrict__ pre) {
    __shared__ float xs[16 * 100];
    const int b = blockIdx.y, tt0 = blockIdx.x * 16, tid = threadIdx.x;
    const int l = tid & 63, wid = tid >> 6, lr = l & 15, lg = l >> 4;
    for (int idx = tid; idx < 1600; idx += 256) {
        int r = idx / 100, k = idx % 100;
        xs[idx] = (k < DIN) ? x[((size_t)b * TT + (TT - 1 - (tt0 + r))) * DIN + k] : 0.f;
    }
    __syncthreads();
    bf16x8 af[3];
    #pragma unroll
    for (int ks = 0; ks < 3; ++ks) af[ks] = fragF32(xs + lr * 100 + ks * 32 + lg * 8);
    const uint4* bt4 = (const uint4*)bt;
    for (int nt = wid; nt < 25; nt += 4) {
        f32x4 acc = {0.f, 0.f, 0.f, 0.f};
        const uint4* bp = bt4 + (size_t)(388 + nt * 3) * 64 + l;
        #pragma unroll
        for (int ks = 0; ks < 3; ++ks) { FU bu; bu.u = *(const u32x4*)(bp + ks * 64); acc = MFMA(af[ks], bu.v, acc); }
        int col = nt * 16 + lr;
        float bias = b_ih[col] + b_hh[col];
        #pragma unroll
        for (int i = 0; i < 4; ++i)
            pre[((size_t)b * TT + tt0 + lg * 4 + i) * DH + col] = acc[i] + bias;
    }
}

// ---------------- serial RNN scan (dot2-VALU, 1 batch/block, 128 blocks) ----------------
// Round-5 structure (proven correct) + round-10 allocation idiom: W as u32x4
// quads, "+v"-pinned, 200 VGPRs/thread at 2 waves/SIMD.
// h_t = relu(pre_t + W_hh h_{t-1}); h carried as packed bf16 in LDS; hs written
// packed-bf16 into the first 200 dwords of the consumed pre row.
#define DLOOP(OFF)                                                              \
    _Pragma("unroll")                                                           \
    for (int d = 0; d < 100; ++d) {                                             \
        const int kd = (OFF) + d;                                               \
        const int hsrc = ((kd >> 6) == 0) ? hl0 : ((kd >> 6) == 1) ? hl1        \
                        : ((kd >> 6) == 2) ? hl2 : hl3;                         \
        int hv = __builtin_amdgcn_readlane(hsrc, kd & 63);                      \
        uint wA = W4[d >> 2][d & 3];                                            \
        uint wB = W4[(100 + d) >> 2][(100 + d) & 3];                            \
        if (d & 1) { DOT2(r0b, wA, hv); DOT2(r1b, wB, hv); }                    \
        else       { DOT2(r0a, wA, hv); DOT2(r1a, wB, hv); }                    \
    }

__global__ __launch_bounds__(512) __attribute__((amdgpu_waves_per_eu(2, 2)))
void rnn_kernel(const u32x4* __restrict__ Wb4, const float* __restrict__ h0,
                float* __restrict__ hs) {
    __shared__ uint h_lds[256];     // packed bf16 pairs; dwords 200..255 zero
    __shared__ float2 part[200];    // k-half-1 partial sums per row-pair

    const int tid = threadIdx.x;
    const int lane = tid & 63;
    const bool a0 = (tid < 200);
    const bool a1 = (tid >= 256) && (tid < 456);
    const int p = a0 ? tid : (a1 ? tid - 256 : 0);

    // W: 50 quads = 200 dwords = 2 rows x 100 k-dwords (this thread's k-half)
    u32x4 W4[50];
    #pragma unroll
    for (int j4 = 0; j4 < 50; ++j4) W4[j4] = Wb4[j4 * 512 + tid];
    #pragma unroll
    for (int j4 = 0; j4 < 50; ++j4) asm volatile("" : "+v"(W4[j4]));

    if (tid < 256)
        h_lds[tid] = (tid < 200) ? pk2(h0[2 * tid], h0[2 * tid + 1]) : 0u;
    __syncthreads();

    float* base = hs + (size_t)blockIdx.x * TT * DH;
    float2 pcur = make_float2(0.f, 0.f);
    if (a0) pcur = *(const float2*)(base + 2 * p);

    for (int tt = 0; tt < TT; ++tt) {
        int hl0 = (int)h_lds[lane];
        int hl1 = (int)h_lds[64 + lane];
        int hl2 = (int)h_lds[128 + lane];
        int hl3 = (int)h_lds[192 + lane];

        float2 pnxt = make_float2(0.f, 0.f);
        if (a0 && tt + 1 < TT) pnxt = *(const float2*)(base + (size_t)(tt + 1) * DH + 2 * p);

        float r0a = 0.f, r0b = 0.f, r1a = 0.f, r1b = 0.f;
        if (a0)      { DLOOP(0) }
        else if (a1) { DLOOP(100) }

        if (a1) part[p] = make_float2(r0a + r0b, r1a + r1b);
        __syncthreads();   // partials visible; all h_lds reads of this step done
        if (a0) {
            float2 q = part[p];
            float v0 = fmaxf(pcur.x + r0a + r0b + q.x, 0.f);
            float v1 = fmaxf(pcur.y + r1a + r1b + q.y, 0.f);
            uint pkd = pk2(v0, v1);
            h_lds[p] = pkd;
            ((uint*)(base + (size_t)tt * DH))[p] = pkd;   // hs (bf16) over consumed pre
            pcur = pnxt;
        }
        __syncthreads();   // h_lds ready for next step
    }
}

// ---------------- fused downstream (MFMA; hs = first 50 uint4 of 100-uint4 rows) ----------------
__global__ __launch_bounds__(256) void e_kernel(
    const uint4* __restrict__ hs4, const float* __restrict__ eps,
    const float* __restrict__ z0, const uint* __restrict__ bt,
    const float* __restrict__ b_loc, const float* __restrict__ b_scale,
    const float* __restrict__ gb1, const float* __restrict__ pb1,
    const float* __restrict__ gb2, const float* __restrict__ pb2,
    const float* __restrict__ lb,  const float* __restrict__ sb,
    const float* __restrict__ eb1, const float* __restrict__ eb2,
    const float* __restrict__ eb3, float* __restrict__ out) {
    __shared__ float lds[12196];
    float* zl = lds;              // [17][100] fp32, cols 80-99 zero
    float* AP = lds + 1700;       // A:[16][228] | P at +3648; zpre overlays (stride 164)
    float* gp = lds + 8996;       // gate [16][100] | prop at +1600

    const int tid = threadIdx.x, l = tid & 63, wid = tid >> 6;
    const int b = blockIdx.y, t0 = blockIdx.x * 16;
    const int lr = l & 15, lg = l >> 4;
    const uint4* bt4 = (const uint4*)bt;

    bf16x8 zf[3];

    // ---- P1: zpre = hs_rows @ [W_loc|W_scale]^T ----
    {
        const int m0 = (wid >> 1) * 16;
        int r = m0 + lr;
        int t = t0 - 1 + r; t = min(max(t, 0), TT - 1);
        const uint4* rp = hs4 + ((size_t)b * TT + (TT - 1 - t)) * 100;
        bf16x8 af[13];
        FU zz; zz.u = (u32x4){0u, 0u, 0u, 0u};
        #pragma unroll
        for (int ks = 0; ks < 13; ++ks) {
            if (ks == 12 && lg >= 2) af[ks] = zz.v;
            else { FU fu; fu.u = *(const u32x4*)(rp + ks * 4 + lg); af[ks] = fu.v; }
        }
        for (int nt = (wid & 1); nt < 10; nt += 2) {
            f32x4 acc = {0.f, 0.f, 0.f, 0.f};
            const uint4* bp = bt4 + (size_t)(nt * 13) * 64 + l;
            #pragma unroll
            for (int ks = 0; ks < 13; ++ks) { FU bu; bu.u = *(const u32x4*)(bp + ks * 64); acc = MFMA(af[ks], bu.v, acc); }
            int col = nt * 16 + lr;
            float bias = (col < DZ) ? b_loc[col] : b_scale[col - DZ];
            #pragma unroll
            for (int i = 0; i < 4; ++i) {
                int rr = m0 + lg * 4 + i;
                if (rr < 17) AP[rr * 164 + col] = acc[i] + bias;
            }
        }
    }
    __syncthreads();

    // ---- P1b: z = zloc + softplus(zscale)*eps ----
    for (int idx = tid; idx < 17 * 100; idx += 256) {
        int r = idx / 100, o = idx % 100;
        float zv = 0.f;
        if (o < DZ) {
            int t = t0 - 1 + r;
            if (t < 0) zv = z0[o];
            else {
                float sp = softplusf(AP[r * 164 + DZ + o]);
                zv = AP[r * 164 + o] + sp * eps[((size_t)b * TT + t) * DZ + o];
            }
        }
        zl[idx] = zv;
    }
    __syncthreads();

    // ---- P2: A/P = relu(z_shift @ {gW1,pW1}^T) ----
    {
        #pragma unroll
        for (int ks = 0; ks < 3; ++ks) zf[ks] = fragF32(zl + lr * 100 + ks * 32 + lg * 8);
        for (int idx = tid; idx < 640; idx += 256) {
            int h = idx / 320, rem = idx % 320;
            AP[h * 3648 + (rem / 20) * 228 + 208 + rem % 20] = 0.f;
        }
        for (int nt = wid; nt < 26; nt += 4) {
            f32x4 acc = {0.f, 0.f, 0.f, 0.f};
            const uint4* bp = bt4 + (size_t)(130 + nt * 3) * 64 + l;
            #pragma unroll
            for (int ks = 0; ks < 3; ++ks) { FU bu; bu.u = *(const u32x4*)(bp + ks * 64); acc = MFMA(zf[ks], bu.v, acc); }
            int isP = nt >= 13;
            int col = (isP ? nt - 13 : nt) * 16 + lr;
            float bias = (col < DTR) ? (isP ? pb1[col] : gb1[col]) : 0.f;
            float* dst = AP + isP * 3648;
            #pragma unroll
            for (int i = 0; i < 4; ++i)
                dst[(lg * 4 + i) * 228 + col] = fmaxf(acc[i] + bias, 0.f);
        }
    }
    __syncthreads();

    // ---- P3: gate = sigmoid(A@gW2^T), prop = P@pW2^T ----
    {
        int half = wid >> 1;
        const float* src = AP + half * 3648;
        bf16x8 apf[7];
        #pragma unroll
        for (int ks = 0; ks < 7; ++ks) apf[ks] = fragF32(src + lr * 228 + ks * 32 + lg * 8);
        for (int idx = tid; idx < 640; idx += 256) {
            int h = idx / 320, rem = idx % 320;
            gp[h * 1600 + (rem / 20) * 100 + 80 + rem % 20] = 0.f;
        }
        for (int nt = (wid & 1); nt < 5; nt += 2) {
            f32x4 acc = {0.f, 0.f, 0.f, 0.f};
            const uint4* bp = bt4 + (size_t)(208 + half * 35 + nt * 7) * 64 + l;
            #pragma unroll
            for (int ks = 0; ks < 7; ++ks) { FU bu; bu.u = *(const u32x4*)(bp + ks * 64); acc = MFMA(apf[ks], bu.v, acc); }
            int col = nt * 16 + lr;
            float bias = half ? pb2[col] : gb2[col];
            float* dst = gp + half * 1600;
            #pragma unroll
            for (int i = 0; i < 4; ++i) {
                float v = acc[i] + bias;
                dst[(lg * 4 + i) * 100 + col] = half ? v : sigmoidf(v);
            }
        }
    }
    __syncthreads();

    // ---- P4 (trans_loc/trans_scale) + P5 (h1) ----
    {
        bf16x8 z1f[3], prf[3];
        #pragma unroll
        for (int ks = 0; ks < 3; ++ks) {
            z1f[ks] = fragF32(zl + (1 + lr) * 100 + ks * 32 + lg * 8);
            prf[ks] = fragF32relu(gp + 1600 + lr * 100 + ks * 32 + lg * 8);
        }
        for (int tsk = wid; tsk < 18; tsk += 4) {
            if (tsk < 5) {
                f32x4 acc = {0.f, 0.f, 0.f, 0.f};
                const uint4* bp = bt4 + (size_t)(278 + tsk * 3) * 64 + l;
                #pragma unroll
                for (int ks = 0; ks < 3; ++ks) { FU bu; bu.u = *(const u32x4*)(bp + ks * 64); acc = MFMA(zf[ks], bu.v, acc); }
                int col = tsk * 16 + lr;
                float bias = lb[col];
                #pragma unroll
                for (int i = 0; i < 4; ++i) {
                    int rr = lg * 4 + i;
                    float g  = gp[rr * 100 + col];
                    float pv = gp[1600 + rr * 100 + col];
                    out[((size_t)b * TT + t0 + rr) * DOUT + DIN + col] =
                        (1.f - g) * (acc[i] + bias) + g * pv;
                }
            } else if (tsk < 10) {
                int nt = tsk - 5;
                f32x4 acc = {0.f, 0.f, 0.f, 0.f};
                const uint4* bp = bt4 + (size_t)(293 + nt * 3) * 64 + l;
                #pragma unroll
                for (int ks = 0; ks < 3; ++ks) { FU bu; bu.u = *(const u32x4*)(bp + ks * 64); acc = MFMA(prf[ks], bu.v, acc); }
                int col = nt * 16 + lr;
                float bias = sb[col];
                #pragma unroll
                for (int i = 0; i < 4; ++i)
                    out[((size_t)b * TT + t0 + lg * 4 + i) * DOUT + DIN + DZ + col] =
                        softplusf(acc[i] + bias);
            } else {
                int nt = tsk - 10;
                f32x4 acc = {0.f, 0.f, 0.f, 0.f};
                const uint4* bp = bt4 + (size_t)(308 + nt * 3) * 64 + l;
                #pragma unroll
                for (int ks = 0; ks < 3; ++ks) { FU bu; bu.u = *(const u32x4*)(bp + ks * 64); acc = MFMA(z1f[ks], bu.v, acc); }
                int col = nt * 16 + lr;
                float bias = (col < DE) ? eb1[col] : 0.f;
                #pragma unroll
                for (int i = 0; i < 4; ++i)
                    AP[(lg * 4 + i) * 228 + col] = fmaxf(acc[i] + bias, 0.f);
            }
        }
    }
    __syncthreads();

    // ---- P6: h2 = relu(h1 @ eW2^T) ----
    {
        bf16x8 hf[4];
        #pragma unroll
        for (int ks = 0; ks < 4; ++ks) hf[ks] = fragF32(AP + lr * 228 + ks * 32 + lg * 8);
        for (int nt = wid; nt < 8; nt += 4) {
            f32x4 acc = {0.f, 0.f, 0.f, 0.f};
            const uint4* bp = bt4 + (size_t)(332 + nt * 4) * 64 + l;
            #pragma unroll
            for (int ks = 0; ks < 4; ++ks) { FU bu; bu.u = *(const u32x4*)(bp + ks * 64); acc = MFMA(hf[ks], bu.v, acc); }
            int col = nt * 16 + lr;
            float bias = (col < DE) ? eb2[col] : 0.f;
            #pragma unroll
            for (int i = 0; i < 4; ++i)
                AP[3648 + (lg * 4 + i) * 228 + col] = fmaxf(acc[i] + bias, 0.f);
        }
    }
    __syncthreads();

    // ---- P7: emis = sigmoid(h2 @ eW3^T) ----
    {
        bf16x8 hf[4];
        #pragma unroll
        for (int ks = 0; ks < 4; ++ks) hf[ks] = fragF32(AP + 3648 + lr * 228 + ks * 32 + lg * 8);
        for (int nt = wid; nt < 6; nt += 4) {
            f32x4 acc = {0.f, 0.f, 0.f, 0.f};
            const uint4* bp = bt4 + (size_t)(364 + nt * 4) * 64 + l;
            #pragma unroll
            for (int ks = 0; ks < 4; ++ks) { FU bu; bu.u = *(const u32x4*)(bp + ks * 64); acc = MFMA(hf[ks], bu.v, acc); }
            int col = nt * 16 + lr;
            if (col < DIN) {
                float bias = eb3[col];
                #pragma unroll
                for (int i = 0; i < 4; ++i)
                    out[((size_t)b * TT + t0 + lg * 4 + i) * DOUT + col] = sigmoidf(acc[i] + bias);
            }
        }
    }
}

extern "C" void kernel_launch(void* const* d_in, const int* in_sizes, int n_in,
                              void* d_out, int out_size, void* d_ws, size_t ws_size,
                              hipStream_t stream) {
    const float* x       = (const float*)d_in[0];
    const float* eps     = (const float*)d_in[1];
    const float* W_ih    = (const float*)d_in[2];
    const float* W_hh    = (const float*)d_in[3];
    const float* b_ih    = (const float*)d_in[4];
    const float* b_hh    = (const float*)d_in[5];
    const float* h0      = (const float*)d_in[6];
    const float* z0      = (const float*)d_in[7];
    const float* W_loc   = (const float*)d_in[8];
    const float* b_loc   = (const float*)d_in[9];
    const float* W_scale = (const float*)d_in[10];
    const float* b_scale = (const float*)d_in[11];
    const float* gW1 = (const float*)d_in[12];
    const float* gb1 = (const float*)d_in[13];
    const float* gW2 = (const float*)d_in[14];
    const float* gb2 = (const float*)d_in[15];
    const float* pW1 = (const float*)d_in[16];
    const float* pb1 = (const float*)d_in[17];
    const float* pW2 = (const float*)d_in[18];
    const float* pb2 = (const float*)d_in[19];
    const float* sW  = (const float*)d_in[20];
    const float* sb  = (const float*)d_in[21];
    const float* lW  = (const float*)d_in[22];
    const float* lb  = (const float*)d_in[23];
    const float* eW1 = (const float*)d_in[24];
    const float* eb1 = (const float*)d_in[25];
    const float* eW2 = (const float*)d_in[26];
    const float* eb2 = (const float*)d_in[27];
    const float* eW3 = (const float*)d_in[28];
    const float* eb3 = (const float*)d_in[29];

    float* wsf = (float*)d_ws;
    float* prebuf = wsf;                               // B*T*DH floats (pre -> hs bf16 in-place)
    uint*  bt = (uint*)(wsf + (size_t)BB * TT * DH);   // 788 tiles * 256 dwords
    uint*  Wb = bt + 788 * 256;                        // 200*512 dwords (dot2 W layout)

    Srcs s;
    s.p[0] = W_loc;  s.p[1] = W_scale; s.p[2] = gW1; s.p[3] = pW1;
    s.p[4] = gW2;    s.p[5] = pW2;     s.p[6] = lW;  s.p[7] = sW;
    s.p[8] = eW1;    s.p[9] = eW2;     s.p[10] = eW3; s.p[11] = W_ih; s.p[12] = W_hh;
    packall_kernel<<<788, 256, 0, stream>>>(s, bt);
    pack_rnn<<<400, 256, 0, stream>>>(W_hh, Wb);

    pre_kernel<<<dim3(TT / 16, BB), 256, 0, stream>>>(x, bt, b_ih, b_hh, prebuf);

    rnn_kernel<<<dim3(BB), dim3(512), 0, stream>>>((const u32x4*)Wb, h0, prebuf);

    e_kernel<<<dim3(TT / 16, BB), 256, 0, stream>>>(
        (const uint4*)prebuf, eps, z0, bt,
        b_loc, b_scale, gb1, pb1, gb2, pb2, lb, sb, eb1, eb2, eb3,
        (float*)d_out);
}

// Round 12
// 1136.273 us; speedup vs baseline: 1.3081x; 1.0122x over previous
//
#include <hip/hip_runtime.h>
#include <math.h>

typedef unsigned int uint;

// Dims
constexpr int BB  = 128;
constexpr int TT  = 512;
constexpr int DIN = 88;
constexpr int DZ  = 80;
constexpr int DH  = 400;
constexpr int DE  = 100;
constexpr int DTR = 200;
constexpr int DOUT = DIN + DZ + DZ; // 248

typedef __attribute__((ext_vector_type(8))) short bf16x8;
typedef __attribute__((ext_vector_type(4))) float f32x4;
typedef __attribute__((ext_vector_type(4))) uint  u32x4;
union FU { u32x4 u; bf16x8 v; };

__device__ __forceinline__ float softplusf(float x) {
    return fmaxf(x, 0.f) + log1pf(__expf(-fabsf(x)));
}
__device__ __forceinline__ float sigmoidf(float x) {
    return 1.f / (1.f + __expf(-x));
}
__device__ __forceinline__ uint bf16rn(float f) {
    uint u = __float_as_uint(f);
    return (u + 0x7FFFu + ((u >> 16) & 1u)) >> 16;
}
__device__ __forceinline__ uint pk2(float lo, float hi) {
    return bf16rn(lo) | (bf16rn(hi) << 16);
}
__device__ __forceinline__ bf16x8 fragF32(const float* p) {
    float4 f0 = *(const float4*)p, f1 = *(const float4*)(p + 4);
    FU fu;
    fu.u.x = pk2(f0.x, f0.y); fu.u.y = pk2(f0.z, f0.w);
    fu.u.z = pk2(f1.x, f1.y); fu.u.w = pk2(f1.z, f1.w);
    return fu.v;
}
__device__ __forceinline__ bf16x8 fragF32relu(const float* p) {
    float4 f0 = *(const float4*)p, f1 = *(const float4*)(p + 4);
    FU fu;
    fu.u.x = pk2(fmaxf(f0.x, 0.f), fmaxf(f0.y, 0.f));
    fu.u.y = pk2(fmaxf(f0.z, 0.f), fmaxf(f0.w, 0.f));
    fu.u.z = pk2(fmaxf(f1.x, 0.f), fmaxf(f1.y, 0.f));
    fu.u.w = pk2(fmaxf(f1.z, 0.f), fmaxf(f1.w, 0.f));
    return fu.v;
}
#define MFMA(A, B, C) __builtin_amdgcn_mfma_f32_16x16x32_bf16((A), (B), (C), 0, 0, 0)

// ---------------- fused weight pack ----------------
struct Srcs { const float* p[13]; };

__global__ __launch_bounds__(256) void packall_kernel(Srcs s, uint* __restrict__ dst) {
    constexpr int O_[13]   = {80,80,200,200,80,80,80,80,100,100,88,400,400};
    constexpr int K_[13]   = {400,400,80,80,200,200,80,80,80,100,100,88,400};
    constexpr int KS_[13]  = {13,13,3,3,7,7,3,3,3,4,4,3,13};
    constexpr int OFF_[13] = {0,65,130,169,208,243,278,293,308,332,364,388,463};
    int tile = blockIdx.x;
    int e = 0;
    #pragma unroll
    for (int i = 1; i < 13; ++i) if (tile >= OFF_[i]) e = i;
    int lt = tile - OFF_[e];
    int nt = lt / KS_[e], ks = lt % KS_[e];
    const float* W = s.p[e];
    int r = threadIdx.x, l = r >> 2, d = r & 3;
    int o = nt * 16 + (l & 15);
    int k = ks * 32 + ((l >> 4) << 3) + 2 * d;
    uint lo = 0, hi = 0;
    if (o < O_[e] && k < K_[e])     lo = bf16rn(W[o * K_[e] + k]);
    if (o < O_[e] && k + 1 < K_[e]) hi = bf16rn(W[o * K_[e] + k + 1]);
    dst[(size_t)tile * 256 + r] = lo | (hi << 16);
}

constexpr int WHH = 463;   // W_hh tiles: WHH + mt*13 + ks; 25 M-tiles

// ---------------- pre GEMM (MFMA), fp32 output ----------------
__global__ __launch_bounds__(256) void pre_kernel(
    const float* __restrict__ x, const uint* __restrict__ bt,
    const float* __restrict__ b_ih, const float* __restrict__ b_hh,
    float* __restrict__ pre) {
    __shared__ float xs[16 * 100];
    const int b = blockIdx.y, tt0 = blockIdx.x * 16, tid = threadIdx.x;
    const int l = tid & 63, wid = tid >> 6, lr = l & 15, lg = l >> 4;
    for (int idx = tid; idx < 1600; idx += 256) {
        int r = idx / 100, k = idx % 100;
        xs[idx] = (k < DIN) ? x[((size_t)b * TT + (TT - 1 - (tt0 + r))) * DIN + k] : 0.f;
    }
    __syncthreads();
    bf16x8 af[3];
    #pragma unroll
    for (int ks = 0; ks < 3; ++ks) af[ks] = fragF32(xs + lr * 100 + ks * 32 + lg * 8);
    const uint4* bt4 = (const uint4*)bt;
    for (int nt = wid; nt < 25; nt += 4) {
        f32x4 acc = {0.f, 0.f, 0.f, 0.f};
        const uint4* bp = bt4 + (size_t)(388 + nt * 3) * 64 + l;
        #pragma unroll
        for (int ks = 0; ks < 3; ++ks) { FU bu; bu.u = *(const u32x4*)(bp + ks * 64); acc = MFMA(af[ks], bu.v, acc); }
        int col = nt * 16 + lr;
        float bias = b_ih[col] + b_hh[col];
        #pragma unroll
        for (int i = 0; i < 4; ++i)
            pre[((size_t)b * TT + tt0 + lg * 4 + i) * DH + col] = acc[i] + bias;
    }
}

// ---------------- serial RNN scan (MFMA, 16 batches/block, 8 blocks) ----------------
// Round-7 proven structure. ONE change: per-step barrier is lgkmcnt(0)+s_barrier
// (no vmcnt drain — hs global stores and staged-pre loads stay in flight across
// the barrier; data deps force their own vmcnt waits where needed).
__global__ __launch_bounds__(512) __attribute__((amdgpu_waves_per_eu(2, 2)))
void rnn_kernel(const u32x4* __restrict__ bt4, const float* __restrict__ h0,
                float* __restrict__ prehs) {
    extern __shared__ char smem[];
    uint*  hb   = (uint*)smem;                       // [2][16][212] packed bf16 h (dwords 200-211 zero pad)
    float* pb   = (float*)(smem + 27136);            // [2][16][404] staged pre (fp32)
    u32x4* wt24 = (u32x4*)(smem + 27136 + 51712);    // [13*64] tile-24 W frags

    const int tid = threadIdx.x, lane = tid & 63, wid = tid >> 6;
    const int batch = lane & 15, lg = lane >> 4;
    const int b0 = blockIdx.x * 16;

    // resident A (W) tiles: wave w owns mt = 3w, 3w+1, 3w+2
    u32x4 A0[13], A1[13], A2[13];
    {
        const u32x4* base = bt4 + (size_t)(WHH + 3 * wid * 13) * 64 + lane;
        #pragma unroll
        for (int ks = 0; ks < 13; ++ks) {
            A0[ks] = base[ks * 64];
            A1[ks] = base[(13 + ks) * 64];
            A2[ks] = base[(26 + ks) * 64];
        }
    }
    #pragma unroll
    for (int ks = 0; ks < 13; ++ks)
        asm volatile("" : "+v"(A0[ks]), "+v"(A1[ks]), "+v"(A2[ks]));

    // stage tile-24 W into LDS
    for (int i = tid; i < 13 * 64; i += 512)
        wt24[i] = bt4[(size_t)(WHH + 24 * 13) * 64 + i];

    // zero hb pad dwords (both buffers), fill h0 into buf0
    for (int i = tid; i < 2 * 16 * 12; i += 512) {
        int buf = i / 192, r = i % 192, bs = r / 12, d = 200 + r % 12;
        hb[buf * 3392 + bs * 212 + d] = 0u;
    }
    for (int i = tid; i < 16 * 200; i += 512) {
        int bs = i / 200, d = i % 200;
        hb[bs * 212 + d] = pk2(h0[2 * d], h0[2 * d + 1]);
    }
    // stage pre_0 (wave w -> batches 2w, 2w+1)
    {
        const u32x4* ra = (const u32x4*)(prehs + ((size_t)(b0 + 2 * wid) * TT) * DH);
        const u32x4* rb = (const u32x4*)(prehs + ((size_t)(b0 + 2 * wid + 1) * TT) * DH);
        u32x4* wa = (u32x4*)(pb + (2 * wid) * 404);
        u32x4* wb = (u32x4*)(pb + (2 * wid + 1) * 404);
        wa[lane] = ra[lane];
        wb[lane] = rb[lane];
        if (lane < 36) { wa[64 + lane] = ra[64 + lane]; wb[64 + lane] = rb[64 + lane]; }
    }
    __syncthreads();

    uint cur = 0;
    for (int tt = 0; tt < TT; ++tt) {
        // issue next-step pre loads early (latency hides under MFMA)
        u32x4 na0, na1, nb0, nb1;
        const bool hasNext = (tt + 1 < TT);
        if (hasNext) {
            const u32x4* ra = (const u32x4*)(prehs + ((size_t)(b0 + 2 * wid) * TT + tt + 1) * DH);
            const u32x4* rb = (const u32x4*)(prehs + ((size_t)(b0 + 2 * wid + 1) * TT + tt + 1) * DH);
            na0 = ra[lane]; nb0 = rb[lane];
            if (lane < 36) { na1 = ra[64 + lane]; nb1 = rb[64 + lane]; }
        }

        const uint*  hcur = hb + cur * 3392;
        const float* pcur = pb + cur * (16 * 404);
        f32x4 c0 = {0.f, 0.f, 0.f, 0.f}, c1 = c0, c2 = c0, c24 = c0;
        const u32x4* hrow = (const u32x4*)(hcur + batch * 212);
        #pragma unroll
        for (int ks = 0; ks < 13; ++ks) {
            FU b; b.u = hrow[ks * 4 + lg];
            FU a0; a0.u = A0[ks]; c0 = MFMA(a0.v, b.v, c0);
            FU a1; a1.u = A1[ks]; c1 = MFMA(a1.v, b.v, c1);
            FU a2; a2.u = A2[ks]; c2 = MFMA(a2.v, b.v, c2);
            if (wid == 7) { FU w; w.u = wt24[ks * 64 + lane]; c24 = MFMA(w.v, b.v, c24); }
        }

        uint*  hnxt = hb + (cur ^ 1) * 3392;
        float* pnxt = pb + (cur ^ 1) * (16 * 404);
        uint*  grow = (uint*)prehs + ((size_t)(b0 + batch) * TT + tt) * DH;

        #pragma unroll
        for (int s = 0; s < 3; ++s) {
            const int mt = 3 * wid + s;
            f32x4 c = (s == 0) ? c0 : (s == 1) ? c1 : c2;
            float4 pr = *(const float4*)(pcur + batch * 404 + mt * 16 + lg * 4);
            uint d0 = pk2(fmaxf(c[0] + pr.x, 0.f), fmaxf(c[1] + pr.y, 0.f));
            uint d1 = pk2(fmaxf(c[2] + pr.z, 0.f), fmaxf(c[3] + pr.w, 0.f));
            uint2 dd = make_uint2(d0, d1);
            *(uint2*)(hnxt + batch * 212 + mt * 8 + lg * 2) = dd;
            *(uint2*)(grow + mt * 8 + lg * 2) = dd;
        }
        if (wid == 7) {
            float4 pr = *(const float4*)(pcur + batch * 404 + 24 * 16 + lg * 4);
            uint d0 = pk2(fmaxf(c24[0] + pr.x, 0.f), fmaxf(c24[1] + pr.y, 0.f));
            uint d1 = pk2(fmaxf(c24[2] + pr.z, 0.f), fmaxf(c24[3] + pr.w, 0.f));
            uint2 dd = make_uint2(d0, d1);
            *(uint2*)(hnxt + batch * 212 + 24 * 8 + lg * 2) = dd;
            *(uint2*)(grow + 24 * 8 + lg * 2) = dd;
        }

        // write staged pre late
        if (hasNext) {
            u32x4* wa = (u32x4*)(pnxt + (2 * wid) * 404);
            u32x4* wb = (u32x4*)(pnxt + (2 * wid + 1) * 404);
            wa[lane] = na0; wb[lane] = nb0;
            if (lane < 36) { wa[64 + lane] = na1; wb[64 + lane] = nb1; }
        }
        // Raw barrier: drain LDS only, leave global stores/loads in flight.
        asm volatile("s_waitcnt lgkmcnt(0)" ::: "memory");
        __builtin_amdgcn_sched_barrier(0);
        __builtin_amdgcn_s_barrier();
        __builtin_amdgcn_sched_barrier(0);
        cur ^= 1;
    }
}

// ---------------- fused downstream (MFMA; hs = first 50 uint4 of 100-uint4 rows) ----------------
__global__ __launch_bounds__(256) void e_kernel(
    const uint4* __restrict__ hs4, const float* __restrict__ eps,
    const float* __restrict__ z0, const uint* __restrict__ bt,
    const float* __restrict__ b_loc, const float* __restrict__ b_scale,
    const float* __restrict__ gb1, const float* __restrict__ pb1,
    const float* __restrict__ gb2, const float* __restrict__ pb2,
    const float* __restrict__ lb,  const float* __restrict__ sb,
    const float* __restrict__ eb1, const float* __restrict__ eb2,
    const float* __restrict__ eb3, float* __restrict__ out) {
    __shared__ float lds[12196];
    float* zl = lds;              // [17][100] fp32, cols 80-99 zero
    float* AP = lds + 1700;       // A:[16][228] | P at +3648; zpre overlays (stride 164)
    float* gp = lds + 8996;       // gate [16][100] | prop at +1600

    const int tid = threadIdx.x, l = tid & 63, wid = tid >> 6;
    const int b = blockIdx.y, t0 = blockIdx.x * 16;
    const int lr = l & 15, lg = l >> 4;
    const uint4* bt4 = (const uint4*)bt;

    bf16x8 zf[3];

    // ---- P1: zpre = hs_rows @ [W_loc|W_scale]^T ----
    {
        const int m0 = (wid >> 1) * 16;
        int r = m0 + lr;
        int t = t0 - 1 + r; t = min(max(t, 0), TT - 1);
        const uint4* rp = hs4 + ((size_t)b * TT + (TT - 1 - t)) * 100;
        bf16x8 af[13];
        FU zz; zz.u = (u32x4){0u, 0u, 0u, 0u};
        #pragma unroll
        for (int ks = 0; ks < 13; ++ks) {
            if (ks == 12 && lg >= 2) af[ks] = zz.v;
            else { FU fu; fu.u = *(const u32x4*)(rp + ks * 4 + lg); af[ks] = fu.v; }
        }
        for (int nt = (wid & 1); nt < 10; nt += 2) {
            f32x4 acc = {0.f, 0.f, 0.f, 0.f};
            const uint4* bp = bt4 + (size_t)(nt * 13) * 64 + l;
            #pragma unroll
            for (int ks = 0; ks < 13; ++ks) { FU bu; bu.u = *(const u32x4*)(bp + ks * 64); acc = MFMA(af[ks], bu.v, acc); }
            int col = nt * 16 + lr;
            float bias = (col < DZ) ? b_loc[col] : b_scale[col - DZ];
            #pragma unroll
            for (int i = 0; i < 4; ++i) {
                int rr = m0 + lg * 4 + i;
                if (rr < 17) AP[rr * 164 + col] = acc[i] + bias;
            }
        }
    }
    __syncthreads();

    // ---- P1b: z = zloc + softplus(zscale)*eps ----
    for (int idx = tid; idx < 17 * 100; idx += 256) {
        int r = idx / 100, o = idx % 100;
        float zv = 0.f;
        if (o < DZ) {
            int t = t0 - 1 + r;
            if (t < 0) zv = z0[o];
            else {
                float sp = softplusf(AP[r * 164 + DZ + o]);
                zv = AP[r * 164 + o] + sp * eps[((size_t)b * TT + t) * DZ + o];
            }
        }
        zl[idx] = zv;
    }
    __syncthreads();

    // ---- P2: A/P = relu(z_shift @ {gW1,pW1}^T) ----
    {
        #pragma unroll
        for (int ks = 0; ks < 3; ++ks) zf[ks] = fragF32(zl + lr * 100 + ks * 32 + lg * 8);
        for (int idx = tid; idx < 640; idx += 256) {
            int h = idx / 320, rem = idx % 320;
            AP[h * 3648 + (rem / 20) * 228 + 208 + rem % 20] = 0.f;
        }
        for (int nt = wid; nt < 26; nt += 4) {
            f32x4 acc = {0.f, 0.f, 0.f, 0.f};
            const uint4* bp = bt4 + (size_t)(130 + nt * 3) * 64 + l;
            #pragma unroll
            for (int ks = 0; ks < 3; ++ks) { FU bu; bu.u = *(const u32x4*)(bp + ks * 64); acc = MFMA(zf[ks], bu.v, acc); }
            int isP = nt >= 13;
            int col = (isP ? nt - 13 : nt) * 16 + lr;
            float bias = (col < DTR) ? (isP ? pb1[col] : gb1[col]) : 0.f;
            float* dst = AP + isP * 3648;
            #pragma unroll
            for (int i = 0; i < 4; ++i)
                dst[(lg * 4 + i) * 228 + col] = fmaxf(acc[i] + bias, 0.f);
        }
    }
    __syncthreads();

    // ---- P3: gate = sigmoid(A@gW2^T), prop = P@pW2^T ----
    {
        int half = wid >> 1;
        const float* src = AP + half * 3648;
        bf16x8 apf[7];
        #pragma unroll
        for (int ks = 0; ks < 7; ++ks) apf[ks] = fragF32(src + lr * 228 + ks * 32 + lg * 8);
        for (int idx = tid; idx < 640; idx += 256) {
            int h = idx / 320, rem = idx % 320;
            gp[h * 1600 + (rem / 20) * 100 + 80 + rem % 20] = 0.f;
        }
        for (int nt = (wid & 1); nt < 5; nt += 2) {
            f32x4 acc = {0.f, 0.f, 0.f, 0.f};
            const uint4* bp = bt4 + (size_t)(208 + half * 35 + nt * 7) * 64 + l;
            #pragma unroll
            for (int ks = 0; ks < 7; ++ks) { FU bu; bu.u = *(const u32x4*)(bp + ks * 64); acc = MFMA(apf[ks], bu.v, acc); }
            int col = nt * 16 + lr;
            float bias = half ? pb2[col] : gb2[col];
            float* dst = gp + half * 1600;
            #pragma unroll
            for (int i = 0; i < 4; ++i) {
                float v = acc[i] + bias;
                dst[(lg * 4 + i) * 100 + col] = half ? v : sigmoidf(v);
            }
        }
    }
    __syncthreads();

    // ---- P4 (trans_loc/trans_scale) + P5 (h1) ----
    {
        bf16x8 z1f[3], prf[3];
        #pragma unroll
        for (int ks = 0; ks < 3; ++ks) {
            z1f[ks] = fragF32(zl + (1 + lr) * 100 + ks * 32 + lg * 8);
            prf[ks] = fragF32relu(gp + 1600 + lr * 100 + ks * 32 + lg * 8);
        }
        for (int tsk = wid; tsk < 18; tsk += 4) {
            if (tsk < 5) {
                f32x4 acc = {0.f, 0.f, 0.f, 0.f};
                const uint4* bp = bt4 + (size_t)(278 + tsk * 3) * 64 + l;
                #pragma unroll
                for (int ks = 0; ks < 3; ++ks) { FU bu; bu.u = *(const u32x4*)(bp + ks * 64); acc = MFMA(zf[ks], bu.v, acc); }
                int col = tsk * 16 + lr;
                float bias = lb[col];
                #pragma unroll
                for (int i = 0; i < 4; ++i) {
                    int rr = lg * 4 + i;
                    float g  = gp[rr * 100 + col];
                    float pv = gp[1600 + rr * 100 + col];
                    out[((size_t)b * TT + t0 + rr) * DOUT + DIN + col] =
                        (1.f - g) * (acc[i] + bias) + g * pv;
                }
            } else if (tsk < 10) {
                int nt = tsk - 5;
                f32x4 acc = {0.f, 0.f, 0.f, 0.f};
                const uint4* bp = bt4 + (size_t)(293 + nt * 3) * 64 + l;
                #pragma unroll
                for (int ks = 0; ks < 3; ++ks) { FU bu; bu.u = *(const u32x4*)(bp + ks * 64); acc = MFMA(prf[ks], bu.v, acc); }
                int col = nt * 16 + lr;
                float bias = sb[col];
                #pragma unroll
                for (int i = 0; i < 4; ++i)
                    out[((size_t)b * TT + t0 + lg * 4 + i) * DOUT + DIN + DZ + col] =
                        softplusf(acc[i] + bias);
            } else {
                int nt = tsk - 10;
                f32x4 acc = {0.f, 0.f, 0.f, 0.f};
                const uint4* bp = bt4 + (size_t)(308 + nt * 3) * 64 + l;
                #pragma unroll
                for (int ks = 0; ks < 3; ++ks) { FU bu; bu.u = *(const u32x4*)(bp + ks * 64); acc = MFMA(z1f[ks], bu.v, acc); }
                int col = nt * 16 + lr;
                float bias = (col < DE) ? eb1[col] : 0.f;
                #pragma unroll
                for (int i = 0; i < 4; ++i)
                    AP[(lg * 4 + i) * 228 + col] = fmaxf(acc[i] + bias, 0.f);
            }
        }
    }
    __syncthreads();

    // ---- P6: h2 = relu(h1 @ eW2^T) ----
    {
        bf16x8 hf[4];
        #pragma unroll
        for (int ks = 0; ks < 4; ++ks) hf[ks] = fragF32(AP + lr * 228 + ks * 32 + lg * 8);
        for (int nt = wid; nt < 8; nt += 4) {
            f32x4 acc = {0.f, 0.f, 0.f, 0.f};
            const uint4* bp = bt4 + (size_t)(332 + nt * 4) * 64 + l;
            #pragma unroll
            for (int ks = 0; ks < 4; ++ks) { FU bu; bu.u = *(const u32x4*)(bp + ks * 64); acc = MFMA(hf[ks], bu.v, acc); }
            int col = nt * 16 + lr;
            float bias = (col < DE) ? eb2[col] : 0.f;
            #pragma unroll
            for (int i = 0; i < 4; ++i)
                AP[3648 + (lg * 4 + i) * 228 + col] = fmaxf(acc[i] + bias, 0.f);
        }
    }
    __syncthreads();

    // ---- P7: emis = sigmoid(h2 @ eW3^T) ----
    {
        bf16x8 hf[4];
        #pragma unroll
        for (int ks = 0; ks < 4; ++ks) hf[ks] = fragF32(AP + 3648 + lr * 228 + ks * 32 + lg * 8);
        for (int nt = wid; nt < 6; nt += 4) {
            f32x4 acc = {0.f, 0.f, 0.f, 0.f};
            const uint4* bp = bt4 + (size_t)(364 + nt * 4) * 64 + l;
            #pragma unroll
            for (int ks = 0; ks < 4; ++ks) { FU bu; bu.u = *(const u32x4*)(bp + ks * 64); acc = MFMA(hf[ks], bu.v, acc); }
            int col = nt * 16 + lr;
            if (col < DIN) {
                float bias = eb3[col];
                #pragma unroll
                for (int i = 0; i < 4; ++i)
                    out[((size_t)b * TT + t0 + lg * 4 + i) * DOUT + col] = sigmoidf(acc[i] + bias);
            }
        }
    }
}

extern "C" void kernel_launch(void* const* d_in, const int* in_sizes, int n_in,
                              void* d_out, int out_size, void* d_ws, size_t ws_size,
                              hipStream_t stream) {
    const float* x       = (const float*)d_in[0];
    const float* eps     = (const float*)d_in[1];
    const float* W_ih    = (const float*)d_in[2];
    const float* W_hh    = (const float*)d_in[3];
    const float* b_ih    = (const float*)d_in[4];
    const float* b_hh    = (const float*)d_in[5];
    const float* h0      = (const float*)d_in[6];
    const float* z0      = (const float*)d_in[7];
    const float* W_loc   = (const float*)d_in[8];
    const float* b_loc   = (const float*)d_in[9];
    const float* W_scale = (const float*)d_in[10];
    const float* b_scale = (const float*)d_in[11];
    const float* gW1 = (const float*)d_in[12];
    const float* gb1 = (const float*)d_in[13];
    const float* gW2 = (const float*)d_in[14];
    const float* gb2 = (const float*)d_in[15];
    const float* pW1 = (const float*)d_in[16];
    const float* pb1 = (const float*)d_in[17];
    const float* pW2 = (const float*)d_in[18];
    const float* pb2 = (const float*)d_in[19];
    const float* sW  = (const float*)d_in[20];
    const float* sb  = (const float*)d_in[21];
    const float* lW  = (const float*)d_in[22];
    const float* lb  = (const float*)d_in[23];
    const float* eW1 = (const float*)d_in[24];
    const float* eb1 = (const float*)d_in[25];
    const float* eW2 = (const float*)d_in[26];
    const float* eb2 = (const float*)d_in[27];
    const float* eW3 = (const float*)d_in[28];
    const float* eb3 = (const float*)d_in[29];

    float* wsf = (float*)d_ws;
    float* prebuf = wsf;                               // B*T*DH floats (pre -> hs bf16 in-place)
    uint*  bt = (uint*)(wsf + (size_t)BB * TT * DH);   // 788 tiles * 256 dwords

    Srcs s;
    s.p[0] = W_loc;  s.p[1] = W_scale; s.p[2] = gW1; s.p[3] = pW1;
    s.p[4] = gW2;    s.p[5] = pW2;     s.p[6] = lW;  s.p[7] = sW;
    s.p[8] = eW1;    s.p[9] = eW2;     s.p[10] = eW3; s.p[11] = W_ih; s.p[12] = W_hh;
    packall_kernel<<<788, 256, 0, stream>>>(s, bt);

    pre_kernel<<<dim3(TT / 16, BB), 256, 0, stream>>>(x, bt, b_ih, b_hh, prebuf);

    size_t smem = 27136 + 51712 + 13312;   // 92160 B
    hipFuncSetAttribute((const void*)rnn_kernel,
                        hipFuncAttributeMaxDynamicSharedMemorySize, (int)smem);
    rnn_kernel<<<dim3(8), dim3(512), smem, stream>>>((const u32x4*)bt, h0, prebuf);

    e_kernel<<<dim3(TT / 16, BB), 256, 0, stream>>>(
        (const uint4*)prebuf, eps, z0, bt,
        b_loc, b_scale, gb1, pb1, gb2, pb2, lb, sb, eb1, eb2, eb3,
        (float*)d_out);
}

// Round 13
// 1044.508 us; speedup vs baseline: 1.4230x; 1.0879x over previous
//
#include <hip/hip_runtime.h>
#include <math.h>

typedef unsigned int uint;

// Dims
constexpr int BB  = 128;
constexpr int TT  = 512;
constexpr int DIN = 88;
constexpr int DZ  = 80;
constexpr int DH  = 400;
constexpr int DE  = 100;
constexpr int DTR = 200;
constexpr int DOUT = DIN + DZ + DZ; // 248

typedef __attribute__((ext_vector_type(8))) short bf16x8;
typedef __attribute__((ext_vector_type(4))) float f32x4;
typedef __attribute__((ext_vector_type(4))) uint  u32x4;
union FU { u32x4 u; bf16x8 v; };

__device__ __forceinline__ float softplusf(float x) {
    return fmaxf(x, 0.f) + log1pf(__expf(-fabsf(x)));
}
__device__ __forceinline__ float sigmoidf(float x) {
    return 1.f / (1.f + __expf(-x));
}
__device__ __forceinline__ uint bf16rn(float f) {
    uint u = __float_as_uint(f);
    return (u + 0x7FFFu + ((u >> 16) & 1u)) >> 16;
}
__device__ __forceinline__ uint pk2(float lo, float hi) {
    return bf16rn(lo) | (bf16rn(hi) << 16);
}
__device__ __forceinline__ bf16x8 fragF32(const float* p) {
    float4 f0 = *(const float4*)p, f1 = *(const float4*)(p + 4);
    FU fu;
    fu.u.x = pk2(f0.x, f0.y); fu.u.y = pk2(f0.z, f0.w);
    fu.u.z = pk2(f1.x, f1.y); fu.u.w = pk2(f1.z, f1.w);
    return fu.v;
}
__device__ __forceinline__ bf16x8 fragF32relu(const float* p) {
    float4 f0 = *(const float4*)p, f1 = *(const float4*)(p + 4);
    FU fu;
    fu.u.x = pk2(fmaxf(f0.x, 0.f), fmaxf(f0.y, 0.f));
    fu.u.y = pk2(fmaxf(f0.z, 0.f), fmaxf(f0.w, 0.f));
    fu.u.z = pk2(fmaxf(f1.x, 0.f), fmaxf(f1.y, 0.f));
    fu.u.w = pk2(fmaxf(f1.z, 0.f), fmaxf(f1.w, 0.f));
    return fu.v;
}
#define MFMA(A, B, C) __builtin_amdgcn_mfma_f32_16x16x32_bf16((A), (B), (C), 0, 0, 0)

// ---------------- fused weight pack ----------------
struct Srcs { const float* p[13]; };

__global__ __launch_bounds__(256) void packall_kernel(Srcs s, uint* __restrict__ dst) {
    constexpr int O_[13]   = {80,80,200,200,80,80,80,80,100,100,88,400,400};
    constexpr int K_[13]   = {400,400,80,80,200,200,80,80,80,100,100,88,400};
    constexpr int KS_[13]  = {13,13,3,3,7,7,3,3,3,4,4,3,13};
    constexpr int OFF_[13] = {0,65,130,169,208,243,278,293,308,332,364,388,463};
    int tile = blockIdx.x;
    int e = 0;
    #pragma unroll
    for (int i = 1; i < 13; ++i) if (tile >= OFF_[i]) e = i;
    int lt = tile - OFF_[e];
    int nt = lt / KS_[e], ks = lt % KS_[e];
    const float* W = s.p[e];
    int r = threadIdx.x, l = r >> 2, d = r & 3;
    int o = nt * 16 + (l & 15);
    int k = ks * 32 + ((l >> 4) << 3) + 2 * d;
    uint lo = 0, hi = 0;
    if (o < O_[e] && k < K_[e])     lo = bf16rn(W[o * K_[e] + k]);
    if (o < O_[e] && k + 1 < K_[e]) hi = bf16rn(W[o * K_[e] + k + 1]);
    dst[(size_t)tile * 256 + r] = lo | (hi << 16);
}

constexpr int WHH = 463;   // W_hh tiles: WHH + mt*13 + ks; 25 M-tiles

// ---------------- pre GEMM (MFMA), fp32 output ----------------
__global__ __launch_bounds__(256) void pre_kernel(
    const float* __restrict__ x, const uint* __restrict__ bt,
    const float* __restrict__ b_ih, const float* __restrict__ b_hh,
    float* __restrict__ pre) {
    __shared__ float xs[16 * 100];
    const int b = blockIdx.y, tt0 = blockIdx.x * 16, tid = threadIdx.x;
    const int l = tid & 63, wid = tid >> 6, lr = l & 15, lg = l >> 4;
    for (int idx = tid; idx < 1600; idx += 256) {
        int r = idx / 100, k = idx % 100;
        xs[idx] = (k < DIN) ? x[((size_t)b * TT + (TT - 1 - (tt0 + r))) * DIN + k] : 0.f;
    }
    __syncthreads();
    bf16x8 af[3];
    #pragma unroll
    for (int ks = 0; ks < 3; ++ks) af[ks] = fragF32(xs + lr * 100 + ks * 32 + lg * 8);
    const uint4* bt4 = (const uint4*)bt;
    for (int nt = wid; nt < 25; nt += 4) {
        f32x4 acc = {0.f, 0.f, 0.f, 0.f};
        const uint4* bp = bt4 + (size_t)(388 + nt * 3) * 64 + l;
        #pragma unroll
        for (int ks = 0; ks < 3; ++ks) { FU bu; bu.u = *(const u32x4*)(bp + ks * 64); acc = MFMA(af[ks], bu.v, acc); }
        int col = nt * 16 + lr;
        float bias = b_ih[col] + b_hh[col];
        #pragma unroll
        for (int i = 0; i < 4; ++i)
            pre[((size_t)b * TT + tt0 + lg * 4 + i) * DH + col] = acc[i] + bias;
    }
}

// ---------------- serial RNN scan (MFMA, 16 batches/block, 8 blocks) ----------------
// Round-12 structure; pb LDS staging replaced by per-lane register prefetch
// gather (each lane loads exactly the 3 (+1) float4 pre values it consumes at
// emit). __syncthreads()'s vmcnt drain is the fence that keeps the in-place
// hs store (row tt, dwords 0-199) from racing the pf loads of row tt.
__global__ __launch_bounds__(512) __attribute__((amdgpu_waves_per_eu(2, 2)))
void rnn_kernel(const u32x4* __restrict__ bt4, const float* __restrict__ h0,
                float* __restrict__ prehs) {
    __shared__ uint  hb[2][3392];       // [2][16][212] packed bf16 h (dwords 200-211 zero pad)
    __shared__ u32x4 wt24[13 * 64];     // tile-24 W frags

    const int tid = threadIdx.x, lane = tid & 63, wid = tid >> 6;
    const int batch = lane & 15, lg = lane >> 4;
    const int b0 = blockIdx.x * 16;

    // resident A (W) tiles: wave w owns mt = 3w, 3w+1, 3w+2
    u32x4 A0[13], A1[13], A2[13];
    {
        const u32x4* base = bt4 + (size_t)(WHH + 3 * wid * 13) * 64 + lane;
        #pragma unroll
        for (int ks = 0; ks < 13; ++ks) {
            A0[ks] = base[ks * 64];
            A1[ks] = base[(13 + ks) * 64];
            A2[ks] = base[(26 + ks) * 64];
        }
    }
    #pragma unroll
    for (int ks = 0; ks < 13; ++ks)
        asm volatile("" : "+v"(A0[ks]), "+v"(A1[ks]), "+v"(A2[ks]));

    // stage tile-24 W into LDS
    for (int i = tid; i < 13 * 64; i += 512)
        wt24[i] = bt4[(size_t)(WHH + 24 * 13) * 64 + i];

    // zero hb pad dwords (both buffers), fill h0 into buf0
    for (int i = tid; i < 2 * 16 * 12; i += 512) {
        int buf = i / 192, r = i % 192, bs = r / 12, d = 200 + r % 12;
        hb[buf][bs * 212 + d] = 0u;
    }
    for (int i = tid; i < 16 * 200; i += 512) {
        int bs = i / 200, d = i % 200;
        hb[0][bs * 212 + d] = pk2(h0[2 * d], h0[2 * d + 1]);
    }

    // per-lane pre gather base (this thread's column positions)
    const float* prow = prehs + ((size_t)(b0 + batch) * TT) * DH + lg * 4;
    const int mt0 = 3 * wid;
    float4 cf0 = *(const float4*)(prow + (mt0 + 0) * 16);
    float4 cf1 = *(const float4*)(prow + (mt0 + 1) * 16);
    float4 cf2 = *(const float4*)(prow + (mt0 + 2) * 16);
    float4 cf3 = make_float4(0.f, 0.f, 0.f, 0.f);
    if (wid == 7) cf3 = *(const float4*)(prow + 24 * 16);
    __syncthreads();

    uint cur = 0;
    for (int tt = 0; tt < TT; ++tt) {
        // issue next-step pre gathers early (hide under MFMA)
        float4 nf0, nf1, nf2, nf3;
        const bool hasNext = (tt + 1 < TT);
        if (hasNext) {
            const float* pr = prow + (size_t)(tt + 1) * DH;
            nf0 = *(const float4*)(pr + (mt0 + 0) * 16);
            nf1 = *(const float4*)(pr + (mt0 + 1) * 16);
            nf2 = *(const float4*)(pr + (mt0 + 2) * 16);
            if (wid == 7) nf3 = *(const float4*)(pr + 24 * 16);
        }

        const uint* hcur = hb[cur];
        f32x4 c0 = {0.f, 0.f, 0.f, 0.f}, c1 = c0, c2 = c0, c24 = c0;
        const u32x4* hrow = (const u32x4*)(hcur + batch * 212);
        #pragma unroll
        for (int ks = 0; ks < 13; ++ks) {
            FU b; b.u = hrow[ks * 4 + lg];
            FU a0; a0.u = A0[ks]; c0 = MFMA(a0.v, b.v, c0);
            FU a1; a1.u = A1[ks]; c1 = MFMA(a1.v, b.v, c1);
            FU a2; a2.u = A2[ks]; c2 = MFMA(a2.v, b.v, c2);
            if (wid == 7) { FU w; w.u = wt24[ks * 64 + lane]; c24 = MFMA(w.v, b.v, c24); }
        }

        uint* hnxt = hb[cur ^ 1];
        uint* grow = (uint*)prehs + ((size_t)(b0 + batch) * TT + tt) * DH;

        #pragma unroll
        for (int s = 0; s < 3; ++s) {
            const int mt = mt0 + s;
            f32x4 c = (s == 0) ? c0 : (s == 1) ? c1 : c2;
            float4 pr = (s == 0) ? cf0 : (s == 1) ? cf1 : cf2;
            uint d0 = pk2(fmaxf(c[0] + pr.x, 0.f), fmaxf(c[1] + pr.y, 0.f));
            uint d1 = pk2(fmaxf(c[2] + pr.z, 0.f), fmaxf(c[3] + pr.w, 0.f));
            uint2 dd = make_uint2(d0, d1);
            *(uint2*)(hnxt + batch * 212 + mt * 8 + lg * 2) = dd;
            *(uint2*)(grow + mt * 8 + lg * 2) = dd;
        }
        if (wid == 7) {
            uint d0 = pk2(fmaxf(c24[0] + cf3.x, 0.f), fmaxf(c24[1] + cf3.y, 0.f));
            uint d1 = pk2(fmaxf(c24[2] + cf3.z, 0.f), fmaxf(c24[3] + cf3.w, 0.f));
            uint2 dd = make_uint2(d0, d1);
            *(uint2*)(hnxt + batch * 212 + 24 * 8 + lg * 2) = dd;
            *(uint2*)(grow + 24 * 8 + lg * 2) = dd;
        }

        if (hasNext) { cf0 = nf0; cf1 = nf1; cf2 = nf2; if (wid == 7) cf3 = nf3; }
        __syncthreads();   // vmcnt+lgkm drain: pf loads complete, hb[cur^1] ready
        cur ^= 1;
    }
}

// ---------------- fused downstream (MFMA; hs = first 50 uint4 of 100-uint4 rows) ----------------
__global__ __launch_bounds__(256) void e_kernel(
    const uint4* __restrict__ hs4, const float* __restrict__ eps,
    const float* __restrict__ z0, const uint* __restrict__ bt,
    const float* __restrict__ b_loc, const float* __restrict__ b_scale,
    const float* __restrict__ gb1, const float* __restrict__ pb1,
    const float* __restrict__ gb2, const float* __restrict__ pb2,
    const float* __restrict__ lb,  const float* __restrict__ sb,
    const float* __restrict__ eb1, const float* __restrict__ eb2,
    const float* __restrict__ eb3, float* __restrict__ out) {
    __shared__ float lds[12196];
    float* zl = lds;              // [17][100] fp32, cols 80-99 zero
    float* AP = lds + 1700;       // A:[16][228] | P at +3648; zpre overlays (stride 164)
    float* gp = lds + 8996;       // gate [16][100] | prop at +1600

    const int tid = threadIdx.x, l = tid & 63, wid = tid >> 6;
    const int b = blockIdx.y, t0 = blockIdx.x * 16;
    const int lr = l & 15, lg = l >> 4;
    const uint4* bt4 = (const uint4*)bt;

    bf16x8 zf[3];

    // ---- P1: zpre = hs_rows @ [W_loc|W_scale]^T ----
    {
        const int m0 = (wid >> 1) * 16;
        int r = m0 + lr;
        int t = t0 - 1 + r; t = min(max(t, 0), TT - 1);
        const uint4* rp = hs4 + ((size_t)b * TT + (TT - 1 - t)) * 100;
        bf16x8 af[13];
        FU zz; zz.u = (u32x4){0u, 0u, 0u, 0u};
        #pragma unroll
        for (int ks = 0; ks < 13; ++ks) {
            if (ks == 12 && lg >= 2) af[ks] = zz.v;
            else { FU fu; fu.u = *(const u32x4*)(rp + ks * 4 + lg); af[ks] = fu.v; }
        }
        for (int nt = (wid & 1); nt < 10; nt += 2) {
            f32x4 acc = {0.f, 0.f, 0.f, 0.f};
            const uint4* bp = bt4 + (size_t)(nt * 13) * 64 + l;
            #pragma unroll
            for (int ks = 0; ks < 13; ++ks) { FU bu; bu.u = *(const u32x4*)(bp + ks * 64); acc = MFMA(af[ks], bu.v, acc); }
            int col = nt * 16 + lr;
            float bias = (col < DZ) ? b_loc[col] : b_scale[col - DZ];
            #pragma unroll
            for (int i = 0; i < 4; ++i) {
                int rr = m0 + lg * 4 + i;
                if (rr < 17) AP[rr * 164 + col] = acc[i] + bias;
            }
        }
    }
    __syncthreads();

    // ---- P1b: z = zloc + softplus(zscale)*eps ----
    for (int idx = tid; idx < 17 * 100; idx += 256) {
        int r = idx / 100, o = idx % 100;
        float zv = 0.f;
        if (o < DZ) {
            int t = t0 - 1 + r;
            if (t < 0) zv = z0[o];
            else {
                float sp = softplusf(AP[r * 164 + DZ + o]);
                zv = AP[r * 164 + o] + sp * eps[((size_t)b * TT + t) * DZ + o];
            }
        }
        zl[idx] = zv;
    }
    __syncthreads();

    // ---- P2: A/P = relu(z_shift @ {gW1,pW1}^T) ----
    {
        #pragma unroll
        for (int ks = 0; ks < 3; ++ks) zf[ks] = fragF32(zl + lr * 100 + ks * 32 + lg * 8);
        for (int idx = tid; idx < 640; idx += 256) {
            int h = idx / 320, rem = idx % 320;
            AP[h * 3648 + (rem / 20) * 228 + 208 + rem % 20] = 0.f;
        }
        for (int nt = wid; nt < 26; nt += 4) {
            f32x4 acc = {0.f, 0.f, 0.f, 0.f};
            const uint4* bp = bt4 + (size_t)(130 + nt * 3) * 64 + l;
            #pragma unroll
            for (int ks = 0; ks < 3; ++ks) { FU bu; bu.u = *(const u32x4*)(bp + ks * 64); acc = MFMA(zf[ks], bu.v, acc); }
            int isP = nt >= 13;
            int col = (isP ? nt - 13 : nt) * 16 + lr;
            float bias = (col < DTR) ? (isP ? pb1[col] : gb1[col]) : 0.f;
            float* dst = AP + isP * 3648;
            #pragma unroll
            for (int i = 0; i < 4; ++i)
                dst[(lg * 4 + i) * 228 + col] = fmaxf(acc[i] + bias, 0.f);
        }
    }
    __syncthreads();

    // ---- P3: gate = sigmoid(A@gW2^T), prop = P@pW2^T ----
    {
        int half = wid >> 1;
        const float* src = AP + half * 3648;
        bf16x8 apf[7];
        #pragma unroll
        for (int ks = 0; ks < 7; ++ks) apf[ks] = fragF32(src + lr * 228 + ks * 32 + lg * 8);
        for (int idx = tid; idx < 640; idx += 256) {
            int h = idx / 320, rem = idx % 320;
            gp[h * 1600 + (rem / 20) * 100 + 80 + rem % 20] = 0.f;
        }
        for (int nt = (wid & 1); nt < 5; nt += 2) {
            f32x4 acc = {0.f, 0.f, 0.f, 0.f};
            const uint4* bp = bt4 + (size_t)(208 + half * 35 + nt * 7) * 64 + l;
            #pragma unroll
            for (int ks = 0; ks < 7; ++ks) { FU bu; bu.u = *(const u32x4*)(bp + ks * 64); acc = MFMA(apf[ks], bu.v, acc); }
            int col = nt * 16 + lr;
            float bias = half ? pb2[col] : gb2[col];
            float* dst = gp + half * 1600;
            #pragma unroll
            for (int i = 0; i < 4; ++i) {
                float v = acc[i] + bias;
                dst[(lg * 4 + i) * 100 + col] = half ? v : sigmoidf(v);
            }
        }
    }
    __syncthreads();

    // ---- P4 (trans_loc/trans_scale) + P5 (h1) ----
    {
        bf16x8 z1f[3], prf[3];
        #pragma unroll
        for (int ks = 0; ks < 3; ++ks) {
            z1f[ks] = fragF32(zl + (1 + lr) * 100 + ks * 32 + lg * 8);
            prf[ks] = fragF32relu(gp + 1600 + lr * 100 + ks * 32 + lg * 8);
        }
        for (int tsk = wid; tsk < 18; tsk += 4) {
            if (tsk < 5) {
                f32x4 acc = {0.f, 0.f, 0.f, 0.f};
                const uint4* bp = bt4 + (size_t)(278 + tsk * 3) * 64 + l;
                #pragma unroll
                for (int ks = 0; ks < 3; ++ks) { FU bu; bu.u = *(const u32x4*)(bp + ks * 64); acc = MFMA(zf[ks], bu.v, acc); }
                int col = tsk * 16 + lr;
                float bias = lb[col];
                #pragma unroll
                for (int i = 0; i < 4; ++i) {
                    int rr = lg * 4 + i;
                    float g  = gp[rr * 100 + col];
                    float pv = gp[1600 + rr * 100 + col];
                    out[((size_t)b * TT + t0 + rr) * DOUT + DIN + col] =
                        (1.f - g) * (acc[i] + bias) + g * pv;
                }
            } else if (tsk < 10) {
                int nt = tsk - 5;
                f32x4 acc = {0.f, 0.f, 0.f, 0.f};
                const uint4* bp = bt4 + (size_t)(293 + nt * 3) * 64 + l;
                #pragma unroll
                for (int ks = 0; ks < 3; ++ks) { FU bu; bu.u = *(const u32x4*)(bp + ks * 64); acc = MFMA(prf[ks], bu.v, acc); }
                int col = nt * 16 + lr;
                float bias = sb[col];
                #pragma unroll
                for (int i = 0; i < 4; ++i)
                    out[((size_t)b * TT + t0 + lg * 4 + i) * DOUT + DIN + DZ + col] =
                        softplusf(acc[i] + bias);
            } else {
                int nt = tsk - 10;
                f32x4 acc = {0.f, 0.f, 0.f, 0.f};
                const uint4* bp = bt4 + (size_t)(308 + nt * 3) * 64 + l;
                #pragma unroll
                for (int ks = 0; ks < 3; ++ks) { FU bu; bu.u = *(const u32x4*)(bp + ks * 64); acc = MFMA(z1f[ks], bu.v, acc); }
                int col = nt * 16 + lr;
                float bias = (col < DE) ? eb1[col] : 0.f;
                #pragma unroll
                for (int i = 0; i < 4; ++i)
                    AP[(lg * 4 + i) * 228 + col] = fmaxf(acc[i] + bias, 0.f);
            }
        }
    }
    __syncthreads();

    // ---- P6: h2 = relu(h1 @ eW2^T) ----
    {
        bf16x8 hf[4];
        #pragma unroll
        for (int ks = 0; ks < 4; ++ks) hf[ks] = fragF32(AP + lr * 228 + ks * 32 + lg * 8);
        for (int nt = wid; nt < 8; nt += 4) {
            f32x4 acc = {0.f, 0.f, 0.f, 0.f};
            const uint4* bp = bt4 + (size_t)(332 + nt * 4) * 64 + l;
            #pragma unroll
            for (int ks = 0; ks < 4; ++ks) { FU bu; bu.u = *(const u32x4*)(bp + ks * 64); acc = MFMA(hf[ks], bu.v, acc); }
            int col = nt * 16 + lr;
            float bias = (col < DE) ? eb2[col] : 0.f;
            #pragma unroll
            for (int i = 0; i < 4; ++i)
                AP[3648 + (lg * 4 + i) * 228 + col] = fmaxf(acc[i] + bias, 0.f);
        }
    }
    __syncthreads();

    // ---- P7: emis = sigmoid(h2 @ eW3^T) ----
    {
        bf16x8 hf[4];
        #pragma unroll
        for (int ks = 0; ks < 4; ++ks) hf[ks] = fragF32(AP + 3648 + lr * 228 + ks * 32 + lg * 8);
        for (int nt = wid; nt < 6; nt += 4) {
            f32x4 acc = {0.f, 0.f, 0.f, 0.f};
            const uint4* bp = bt4 + (size_t)(364 + nt * 4) * 64 + l;
            #pragma unroll
            for (int ks = 0; ks < 4; ++ks) { FU bu; bu.u = *(const u32x4*)(bp + ks * 64); acc = MFMA(hf[ks], bu.v, acc); }
            int col = nt * 16 + lr;
            if (col < DIN) {
                float bias = eb3[col];
                #pragma unroll
                for (int i = 0; i < 4; ++i)
                    out[((size_t)b * TT + t0 + lg * 4 + i) * DOUT + col] = sigmoidf(acc[i] + bias);
            }
        }
    }
}

extern "C" void kernel_launch(void* const* d_in, const int* in_sizes, int n_in,
                              void* d_out, int out_size, void* d_ws, size_t ws_size,
                              hipStream_t stream) {
    const float* x       = (const float*)d_in[0];
    const float* eps     = (const float*)d_in[1];
    const float* W_ih    = (const float*)d_in[2];
    const float* W_hh    = (const float*)d_in[3];
    const float* b_ih    = (const float*)d_in[4];
    const float* b_hh    = (const float*)d_in[5];
    const float* h0      = (const float*)d_in[6];
    const float* z0      = (const float*)d_in[7];
    const float* W_loc   = (const float*)d_in[8];
    const float* b_loc   = (const float*)d_in[9];
    const float* W_scale = (const float*)d_in[10];
    const float* b_scale = (const float*)d_in[11];
    const float* gW1 = (const float*)d_in[12];
    const float* gb1 = (const float*)d_in[13];
    const float* gW2 = (const float*)d_in[14];
    const float* gb2 = (const float*)d_in[15];
    const float* pW1 = (const float*)d_in[16];
    const float* pb1 = (const float*)d_in[17];
    const float* pW2 = (const float*)d_in[18];
    const float* pb2 = (const float*)d_in[19];
    const float* sW  = (const float*)d_in[20];
    const float* sb  = (const float*)d_in[21];
    const float* lW  = (const float*)d_in[22];
    const float* lb  = (const float*)d_in[23];
    const float* eW1 = (const float*)d_in[24];
    const float* eb1 = (const float*)d_in[25];
    const float* eW2 = (const float*)d_in[26];
    const float* eb2 = (const float*)d_in[27];
    const float* eW3 = (const float*)d_in[28];
    const float* eb3 = (const float*)d_in[29];

    float* wsf = (float*)d_ws;
    float* prebuf = wsf;                               // B*T*DH floats (pre -> hs bf16 in-place)
    uint*  bt = (uint*)(wsf + (size_t)BB * TT * DH);   // 788 tiles * 256 dwords

    Srcs s;
    s.p[0] = W_loc;  s.p[1] = W_scale; s.p[2] = gW1; s.p[3] = pW1;
    s.p[4] = gW2;    s.p[5] = pW2;     s.p[6] = lW;  s.p[7] = sW;
    s.p[8] = eW1;    s.p[9] = eW2;     s.p[10] = eW3; s.p[11] = W_ih; s.p[12] = W_hh;
    packall_kernel<<<788, 256, 0, stream>>>(s, bt);

    pre_kernel<<<dim3(TT / 16, BB), 256, 0, stream>>>(x, bt, b_ih, b_hh, prebuf);

    rnn_kernel<<<dim3(8), dim3(512), 0, stream>>>((const u32x4*)bt, h0, prebuf);

    e_kernel<<<dim3(TT / 16, BB), 256, 0, stream>>>(
        (const uint4*)prebuf, eps, z0, bt,
        b_loc, b_scale, gb1, pb1, gb2, pb2, lb, sb, eb1, eb2, eb3,
        (float*)d_out);
}